// Round 1
// baseline (930.905 us; speedup 1.0000x reference)
//
#include <hip/hip_runtime.h>

#define NN 50000
#define NE 800000
#define DD 256
#define DE_DIM 16
#define HH 4
#define FF 32
#define HF 128
#define OUTD 32
#define SLOPE 0.2f

// ---- monotonic float<->uint encoding for atomicMax on floats ----
__device__ __forceinline__ unsigned fenc(float f) {
  unsigned u = __float_as_uint(f);
  return u ^ ((u >> 31) ? 0xFFFFFFFFu : 0x80000000u);
}
__device__ __forceinline__ float fdec(unsigned u) {
  unsigned b = (u >> 31) ? (u ^ 0x80000000u) : ~u;
  return __uint_as_float(b);
}

// ---- Kernel 1: node projections ----
// fc_src = feat @ W_src            [N,128]
// fc_dst = feat @ W_dst + b_dst    [N,128]
// asrc   = feat @ W_attn_src       [N,4]
// adst   = feat @ W_attn_dst       [N,4]
// One block = 16 nodes staged in LDS; each thread owns 1-2 output columns
// of the concatenated 264-wide weight matrix; weight reads are coalesced,
// LDS reads are wave-broadcast.
__global__ __launch_bounds__(256) void node_proj_kernel(
    const float* __restrict__ feat,
    const float* __restrict__ Wsrc,
    const float* __restrict__ Wdst, const float* __restrict__ bdst,
    const float* __restrict__ Wasrc, const float* __restrict__ Wadst,
    float* __restrict__ fc_src, float* __restrict__ fc_dst,
    float* __restrict__ asrc, float* __restrict__ adst)
{
  __shared__ float rows[16][DD];
  const int n0 = blockIdx.x * 16;
  const int tid = threadIdx.x;
  for (int i = tid; i < 16 * DD; i += 256) {
    int n = i >> 8, k = i & (DD - 1);
    rows[n][k] = feat[(size_t)(n0 + n) * DD + k];
  }
  __syncthreads();

  for (int c = tid; c < 264; c += 256) {
    const float* W; float* out; int ldw, ldo, cc; float bias = 0.f;
    if (c < 128)      { W = Wsrc + c;          ldw = HF; out = fc_src; ldo = HF; cc = c; }
    else if (c < 256) { W = Wdst + (c - 128);  ldw = HF; out = fc_dst; ldo = HF; cc = c - 128; bias = bdst[cc]; }
    else if (c < 260) { W = Wasrc + (c - 256); ldw = HH; out = asrc;   ldo = HH; cc = c - 256; }
    else              { W = Wadst + (c - 260); ldw = HH; out = adst;   ldo = HH; cc = c - 260; }

    float acc[16];
#pragma unroll
    for (int n = 0; n < 16; ++n) acc[n] = 0.f;

    for (int k0 = 0; k0 < DD; k0 += 4) {
      float w0 = W[(k0 + 0) * ldw];
      float w1 = W[(k0 + 1) * ldw];
      float w2 = W[(k0 + 2) * ldw];
      float w3 = W[(k0 + 3) * ldw];
#pragma unroll
      for (int n = 0; n < 16; ++n) {
        const float4 r = *(const float4*)&rows[n][k0];
        acc[n] += r.x * w0 + r.y * w1 + r.z * w2 + r.w * w3;
      }
    }
#pragma unroll
    for (int n = 0; n < 16; ++n)
      out[(size_t)(n0 + n) * ldo + cc] = acc[n] + bias;
  }
}

// ---- Kernel 2: per-edge logits + segment max (atomicMax on encoded float) ----
__global__ __launch_bounds__(256) void edge_pass1_kernel(
    const float* __restrict__ feat_edge, const float* __restrict__ Wae, // [16,4]
    const int* __restrict__ src_idx, const int* __restrict__ dst_idx,
    const float* __restrict__ asrc, const float* __restrict__ adst,
    float* __restrict__ ebuf, unsigned* __restrict__ emax)
{
  int e = blockIdx.x * 256 + threadIdx.x;
  if (e >= NE) return;
  int s = src_idx[e], d = dst_idx[e];

  float ae[HH] = {0.f, 0.f, 0.f, 0.f};
  const float4* fe4 = (const float4*)(feat_edge + (size_t)e * DE_DIM);
#pragma unroll
  for (int q = 0; q < 4; ++q) {
    float4 x = fe4[q];
    const float xs[4] = {x.x, x.y, x.z, x.w};
#pragma unroll
    for (int kk = 0; kk < 4; ++kk) {
      int k = q * 4 + kk;
#pragma unroll
      for (int h = 0; h < HH; ++h) ae[h] += xs[kk] * Wae[k * HH + h];
    }
  }
  float as[4], ad[4];
  *(float4*)as = *(const float4*)(asrc + (size_t)s * 4);
  *(float4*)ad = *(const float4*)(adst + (size_t)d * 4);

  float ev[4];
#pragma unroll
  for (int h = 0; h < HH; ++h) {
    float v = as[h] + ad[h] + ae[h];
    v = v >= 0.f ? v : SLOPE * v;
    ev[h] = v;
    atomicMax(&emax[(size_t)d * 4 + h], fenc(v));
  }
  *(float4*)(ebuf + (size_t)e * 4) = *(float4*)ev;
}

// ---- Kernel 3: z = exp(e - max), segment sum ----
__global__ __launch_bounds__(256) void edge_pass2_kernel(
    const int* __restrict__ dst_idx, const unsigned* __restrict__ emax,
    float* __restrict__ ebuf, float* __restrict__ zsum)
{
  int e = blockIdx.x * 256 + threadIdx.x;
  if (e >= NE) return;
  int d = dst_idx[e];
  float ev[4];
  *(float4*)ev = *(const float4*)(ebuf + (size_t)e * 4);
#pragma unroll
  for (int h = 0; h < HH; ++h) {
    float m = fdec(emax[(size_t)d * 4 + h]);
    float z = expf(ev[h] - m);
    ev[h] = z;
    atomicAdd(&zsum[(size_t)d * 4 + h], z);
  }
  *(float4*)(ebuf + (size_t)e * 4) = *(float4*)ev;
}

// ---- Kernel 4: weighted message scatter (the heavy one) ----
// 128 threads per edge (one per feature), atomicAdd into h_out[dst].
__global__ __launch_bounds__(256) void edge_agg_kernel(
    const int* __restrict__ src_idx, const int* __restrict__ dst_idx,
    const float* __restrict__ zbuf, const float* __restrict__ zsum,
    const float* __restrict__ fc_src, float* __restrict__ h_out)
{
  long idx = (long)blockIdx.x * 256 + threadIdx.x;
  int e = (int)(idx >> 7);
  if (e >= NE) return;
  int f = (int)(idx & 127);
  int s = src_idx[e], d = dst_idx[e];
  int h = f >> 5;
  float a = zbuf[(size_t)e * 4 + h] / zsum[(size_t)d * 4 + h];
  float v = fc_src[(size_t)s * HF + f] * a;
  atomicAdd(&h_out[(size_t)d * HF + f], v);
}

// ---- Kernel 5: per-head LN + W_agg GEMV + residual + W_apply GEMV ----
// 4 nodes per 128-thread block to amortize W_agg reads.
__global__ __launch_bounds__(128) void node_final_kernel(
    const float* __restrict__ h_in, const float* __restrict__ scale,
    const float* __restrict__ offset, const float* __restrict__ W_agg,
    const float* __restrict__ b_agg, const float* __restrict__ fc_dst,
    const float* __restrict__ W_apply, const float* __restrict__ b_apply,
    float* __restrict__ out)
{
  const int n0 = blockIdx.x * 4;
  const int t = threadIdx.x;
  __shared__ float hn[4][HF];
  __shared__ float rst[4][HF];
  const float sc = scale[t], of = offset[t];

#pragma unroll
  for (int nn = 0; nn < 4; ++nn) {
    float h = h_in[(size_t)(n0 + nn) * HF + t];
    float sum = h;
#pragma unroll
    for (int m = 1; m < 32; m <<= 1) sum += __shfl_xor(sum, m);
    float mean = sum * (1.f / 32.f);
    float dv = h - mean;
    float v2 = dv * dv;
#pragma unroll
    for (int m = 1; m < 32; m <<= 1) v2 += __shfl_xor(v2, m);
    float var = v2 * (1.f / 32.f) + 1e-9f;
    hn[nn][t] = dv * sc * rsqrtf(var) + of;
  }
  __syncthreads();

  float ba = b_agg[t];
  float acc[4] = {ba, ba, ba, ba};
  for (int k = 0; k < HF; ++k) {
    float w = W_agg[k * HF + t];
#pragma unroll
    for (int nn = 0; nn < 4; ++nn) acc[nn] += hn[nn][k] * w;
  }
#pragma unroll
  for (int nn = 0; nn < 4; ++nn) {
    float r = acc[nn] + fc_dst[(size_t)(n0 + nn) * HF + t];
    rst[nn][t] = r >= 0.f ? r : SLOPE * r;
  }
  __syncthreads();

  {
    int nn = t >> 5, c = t & 31;
    float o = b_apply[c];
    for (int k = 0; k < HF; ++k) o += rst[nn][k] * W_apply[k * OUTD + c];
    out[(size_t)(n0 + nn) * OUTD + c] = o;
  }
}

extern "C" void kernel_launch(void* const* d_in, const int* in_sizes, int n_in,
                              void* d_out, int out_size, void* d_ws, size_t ws_size,
                              hipStream_t stream)
{
  const float* feat_src    = (const float*)d_in[0];
  const float* feat_edge   = (const float*)d_in[1];
  const int*   src_idx     = (const int*)d_in[2];
  const int*   dst_idx     = (const int*)d_in[3];
  const float* W_src       = (const float*)d_in[4];
  const float* W_attn_src  = (const float*)d_in[5];
  const float* W_attn_dst  = (const float*)d_in[6];
  const float* W_attn_edge = (const float*)d_in[7];
  const float* scale       = (const float*)d_in[8];
  const float* offset      = (const float*)d_in[9];
  const float* W_agg       = (const float*)d_in[10];
  const float* b_agg       = (const float*)d_in[11];
  const float* W_dst       = (const float*)d_in[12];
  const float* b_dst       = (const float*)d_in[13];
  const float* W_apply     = (const float*)d_in[14];
  const float* b_apply     = (const float*)d_in[15];
  float* out = (float*)d_out;

  char* ws = (char*)d_ws;
  size_t off = 0;
  auto take = [&](size_t bytes) {
    size_t o = off;
    off = (off + bytes + 255) & ~(size_t)255;
    return o;
  };
  size_t fc_src_off = take((size_t)NN * HF * 4);
  size_t fc_dst_off = take((size_t)NN * HF * 4);
  size_t asrc_off   = take((size_t)NN * 4 * 4);
  size_t adst_off   = take((size_t)NN * 4 * 4);
  size_t ebuf_off   = take((size_t)NE * 4 * 4);
  size_t emax_off   = take((size_t)NN * 4 * 4);   // zeroed region starts here
  size_t zsum_off   = take((size_t)NN * 4 * 4);
  size_t hout_off   = take((size_t)NN * HF * 4);
  if (ws_size < off) return;  // workspace too small -> loud failure

  float*    fc_src = (float*)(ws + fc_src_off);
  float*    fc_dst = (float*)(ws + fc_dst_off);
  float*    asrc   = (float*)(ws + asrc_off);
  float*    adst   = (float*)(ws + adst_off);
  float*    ebuf   = (float*)(ws + ebuf_off);
  unsigned* emax   = (unsigned*)(ws + emax_off);
  float*    zsum   = (float*)(ws + zsum_off);
  float*    h_out  = (float*)(ws + hout_off);

  // zero the accumulators (emax encoding: 0 == -NaN == identity for encoded max)
  hipMemsetAsync(ws + emax_off, 0, off - emax_off, stream);

  node_proj_kernel<<<NN / 16, 256, 0, stream>>>(
      feat_src, W_src, W_dst, b_dst, W_attn_src, W_attn_dst,
      fc_src, fc_dst, asrc, adst);

  edge_pass1_kernel<<<(NE + 255) / 256, 256, 0, stream>>>(
      feat_edge, W_attn_edge, src_idx, dst_idx, asrc, adst, ebuf, emax);

  edge_pass2_kernel<<<(NE + 255) / 256, 256, 0, stream>>>(
      dst_idx, emax, ebuf, zsum);

  edge_agg_kernel<<<(long)NE * HF / 256, 256, 0, stream>>>(
      src_idx, dst_idx, ebuf, zsum, fc_src, h_out);

  node_final_kernel<<<NN / 4, 128, 0, stream>>>(
      h_out, scale, offset, W_agg, b_agg, fc_dst, W_apply, b_apply, out);
}

// Round 2
// 759.742 us; speedup vs baseline: 1.2253x; 1.2253x over previous
//
#include <hip/hip_runtime.h>

#define NN 50000
#define NE 800000
#define DD 256
#define DE_DIM 16
#define HH 4
#define FF 32
#define HF 128
#define OUTD 32
#define SLOPE 0.2f
#define NB_SCAN ((NN + 255) / 256)   // 196

// ---- monotonic float<->uint encoding for atomicMax on floats ----
__device__ __forceinline__ unsigned fenc(float f) {
  unsigned u = __float_as_uint(f);
  return u ^ ((u >> 31) ? 0xFFFFFFFFu : 0x80000000u);
}
__device__ __forceinline__ float fdec(unsigned u) {
  unsigned b = (u >> 31) ? (u ^ 0x80000000u) : ~u;
  return __uint_as_float(b);
}

// ---- Kernel 1: node projections (unchanged from R1) ----
__global__ __launch_bounds__(256) void node_proj_kernel(
    const float* __restrict__ feat,
    const float* __restrict__ Wsrc,
    const float* __restrict__ Wdst, const float* __restrict__ bdst,
    const float* __restrict__ Wasrc, const float* __restrict__ Wadst,
    float* __restrict__ fc_src, float* __restrict__ fc_dst,
    float* __restrict__ asrc, float* __restrict__ adst)
{
  __shared__ float rows[16][DD];
  const int n0 = blockIdx.x * 16;
  const int tid = threadIdx.x;
  for (int i = tid; i < 16 * DD; i += 256) {
    int n = i >> 8, k = i & (DD - 1);
    rows[n][k] = feat[(size_t)(n0 + n) * DD + k];
  }
  __syncthreads();

  for (int c = tid; c < 264; c += 256) {
    const float* W; float* out; int ldw, ldo, cc; float bias = 0.f;
    if (c < 128)      { W = Wsrc + c;          ldw = HF; out = fc_src; ldo = HF; cc = c; }
    else if (c < 256) { W = Wdst + (c - 128);  ldw = HF; out = fc_dst; ldo = HF; cc = c - 128; bias = bdst[cc]; }
    else if (c < 260) { W = Wasrc + (c - 256); ldw = HH; out = asrc;   ldo = HH; cc = c - 256; }
    else              { W = Wadst + (c - 260); ldw = HH; out = adst;   ldo = HH; cc = c - 260; }

    float acc[16];
#pragma unroll
    for (int n = 0; n < 16; ++n) acc[n] = 0.f;

    for (int k0 = 0; k0 < DD; k0 += 4) {
      float w0 = W[(k0 + 0) * ldw];
      float w1 = W[(k0 + 1) * ldw];
      float w2 = W[(k0 + 2) * ldw];
      float w3 = W[(k0 + 3) * ldw];
#pragma unroll
      for (int n = 0; n < 16; ++n) {
        const float4 r = *(const float4*)&rows[n][k0];
        acc[n] += r.x * w0 + r.y * w1 + r.z * w2 + r.w * w3;
      }
    }
#pragma unroll
    for (int n = 0; n < 16; ++n)
      out[(size_t)(n0 + n) * ldo + cc] = acc[n] + bias;
  }
}

// ---- Kernel 2: per-edge logits + segment max + dst-degree histogram ----
__global__ __launch_bounds__(256) void edge_pass1_kernel(
    const float* __restrict__ feat_edge, const float* __restrict__ Wae, // [16,4]
    const int* __restrict__ src_idx, const int* __restrict__ dst_idx,
    const float* __restrict__ asrc, const float* __restrict__ adst,
    float* __restrict__ ebuf, unsigned* __restrict__ emax,
    int* __restrict__ cnt)
{
  int e = blockIdx.x * 256 + threadIdx.x;
  if (e >= NE) return;
  int s = src_idx[e], d = dst_idx[e];

  float ae[HH] = {0.f, 0.f, 0.f, 0.f};
  const float4* fe4 = (const float4*)(feat_edge + (size_t)e * DE_DIM);
#pragma unroll
  for (int q = 0; q < 4; ++q) {
    float4 x = fe4[q];
    const float xs[4] = {x.x, x.y, x.z, x.w};
#pragma unroll
    for (int kk = 0; kk < 4; ++kk) {
      int k = q * 4 + kk;
#pragma unroll
      for (int h = 0; h < HH; ++h) ae[h] += xs[kk] * Wae[k * HH + h];
    }
  }
  float as[4], ad[4];
  *(float4*)as = *(const float4*)(asrc + (size_t)s * 4);
  *(float4*)ad = *(const float4*)(adst + (size_t)d * 4);

  float ev[4];
#pragma unroll
  for (int h = 0; h < HH; ++h) {
    float v = as[h] + ad[h] + ae[h];
    v = v >= 0.f ? v : SLOPE * v;
    ev[h] = v;
    atomicMax(&emax[(size_t)d * 4 + h], fenc(v));
  }
  *(float4*)(ebuf + (size_t)e * 4) = *(float4*)ev;
  atomicAdd(&cnt[d], 1);
}

// ---- Kernel 3: z = exp(e - max), segment sum ----
__global__ __launch_bounds__(256) void edge_pass2_kernel(
    const int* __restrict__ dst_idx, const unsigned* __restrict__ emax,
    float* __restrict__ ebuf, float* __restrict__ zsum)
{
  int e = blockIdx.x * 256 + threadIdx.x;
  if (e >= NE) return;
  int d = dst_idx[e];
  float ev[4];
  *(float4*)ev = *(const float4*)(ebuf + (size_t)e * 4);
#pragma unroll
  for (int h = 0; h < HH; ++h) {
    float m = fdec(emax[(size_t)d * 4 + h]);
    float z = expf(ev[h] - m);
    ev[h] = z;
    atomicAdd(&zsum[(size_t)d * 4 + h], z);
  }
  *(float4*)(ebuf + (size_t)e * 4) = *(float4*)ev;
}

// ---- CSR scan: block-local exclusive scan ----
__global__ __launch_bounds__(256) void scan_block_kernel(
    const int* __restrict__ cnt, int* __restrict__ offs, int* __restrict__ bsum)
{
  __shared__ int tmp[256];
  int t = threadIdx.x;
  int i = blockIdx.x * 256 + t;
  int v = (i < NN) ? cnt[i] : 0;
  tmp[t] = v;
  __syncthreads();
  for (int ofs = 1; ofs < 256; ofs <<= 1) {
    int add = (t >= ofs) ? tmp[t - ofs] : 0;
    __syncthreads();
    tmp[t] += add;
    __syncthreads();
  }
  if (i < NN) offs[i] = tmp[t] - v;   // exclusive, block-local
  if (t == 255) bsum[blockIdx.x] = tmp[255];
}

// ---- scan of block sums (single block; NB_SCAN <= 256) ----
__global__ __launch_bounds__(256) void scan_bsum_kernel(
    const int* __restrict__ bsum, int* __restrict__ boff)
{
  __shared__ int tmp[256];
  int t = threadIdx.x;
  int v = (t < NB_SCAN) ? bsum[t] : 0;
  tmp[t] = v;
  __syncthreads();
  for (int ofs = 1; ofs < 256; ofs <<= 1) {
    int add = (t >= ofs) ? tmp[t - ofs] : 0;
    __syncthreads();
    tmp[t] += add;
    __syncthreads();
  }
  if (t < NB_SCAN) boff[t] = tmp[t] - v;
}

// ---- finalize offsets; init scatter cursors ----
__global__ __launch_bounds__(256) void scan_final_kernel(
    int* __restrict__ offs, const int* __restrict__ boff, int* __restrict__ offcur)
{
  int i = blockIdx.x * 256 + threadIdx.x;
  if (i < NN) {
    int o = offs[i] + boff[blockIdx.x];
    offs[i] = o;
    offcur[i] = o;
  }
  if (i == 0) offs[NN] = NE;
}

// ---- scatter edges into CSR order with pre-normalized attention ----
__global__ __launch_bounds__(256) void scatter_kernel(
    const int* __restrict__ src_idx, const int* __restrict__ dst_idx,
    const float* __restrict__ ebuf, const float* __restrict__ zsum,
    int* __restrict__ offcur, int* __restrict__ src_sorted,
    float* __restrict__ a_sorted)
{
  int e = blockIdx.x * 256 + threadIdx.x;
  if (e >= NE) return;
  int d = dst_idx[e];
  int p = atomicAdd(&offcur[d], 1);
  float4 z  = *(const float4*)(ebuf + (size_t)e * 4);
  float4 zs = *(const float4*)(zsum + (size_t)d * 4);
  float4 a;
  a.x = z.x / zs.x; a.y = z.y / zs.y; a.z = z.z / zs.z; a.w = z.w / zs.w;
  src_sorted[p] = src_idx[e];
  *(float4*)(a_sorted + (size_t)p * 4) = a;
}

// ---- Kernel 4': gather-side aggregation, no atomics ----
// One 128-thread block per dst node; thread t owns feature t.
__global__ __launch_bounds__(128) void agg_kernel(
    const int* __restrict__ offs, const int* __restrict__ src_sorted,
    const float* __restrict__ a_sorted, const float* __restrict__ fc_src,
    float* __restrict__ h_out)
{
  const int d = blockIdx.x;
  const int t = threadIdx.x;
  const int h = t >> 5;
  const int beg = offs[d], end = offs[d + 1];
  float acc = 0.f;
  for (int p = beg; p < end; ++p) {
    int s = src_sorted[p];
    float a = a_sorted[(size_t)p * 4 + h];
    acc += fc_src[(size_t)s * HF + t] * a;
  }
  h_out[(size_t)d * HF + t] = acc;
}

// ---- Kernel 5: per-head LN + W_agg GEMV + residual + W_apply GEMV ----
__global__ __launch_bounds__(128) void node_final_kernel(
    const float* __restrict__ h_in, const float* __restrict__ scale,
    const float* __restrict__ offset, const float* __restrict__ W_agg,
    const float* __restrict__ b_agg, const float* __restrict__ fc_dst,
    const float* __restrict__ W_apply, const float* __restrict__ b_apply,
    float* __restrict__ out)
{
  const int n0 = blockIdx.x * 4;
  const int t = threadIdx.x;
  __shared__ float hn[4][HF];
  __shared__ float rst[4][HF];
  const float sc = scale[t], of = offset[t];

#pragma unroll
  for (int nn = 0; nn < 4; ++nn) {
    float h = h_in[(size_t)(n0 + nn) * HF + t];
    float sum = h;
#pragma unroll
    for (int m = 1; m < 32; m <<= 1) sum += __shfl_xor(sum, m);
    float mean = sum * (1.f / 32.f);
    float dv = h - mean;
    float v2 = dv * dv;
#pragma unroll
    for (int m = 1; m < 32; m <<= 1) v2 += __shfl_xor(v2, m);
    float var = v2 * (1.f / 32.f) + 1e-9f;
    hn[nn][t] = dv * sc * rsqrtf(var) + of;
  }
  __syncthreads();

  float ba = b_agg[t];
  float acc[4] = {ba, ba, ba, ba};
  for (int k = 0; k < HF; ++k) {
    float w = W_agg[k * HF + t];
#pragma unroll
    for (int nn = 0; nn < 4; ++nn) acc[nn] += hn[nn][k] * w;
  }
#pragma unroll
  for (int nn = 0; nn < 4; ++nn) {
    float r = acc[nn] + fc_dst[(size_t)(n0 + nn) * HF + t];
    rst[nn][t] = r >= 0.f ? r : SLOPE * r;
  }
  __syncthreads();

  {
    int nn = t >> 5, c = t & 31;
    float o = b_apply[c];
    for (int k = 0; k < HF; ++k) o += rst[nn][k] * W_apply[k * OUTD + c];
    out[(size_t)(n0 + nn) * OUTD + c] = o;
  }
}

extern "C" void kernel_launch(void* const* d_in, const int* in_sizes, int n_in,
                              void* d_out, int out_size, void* d_ws, size_t ws_size,
                              hipStream_t stream)
{
  const float* feat_src    = (const float*)d_in[0];
  const float* feat_edge   = (const float*)d_in[1];
  const int*   src_idx     = (const int*)d_in[2];
  const int*   dst_idx     = (const int*)d_in[3];
  const float* W_src       = (const float*)d_in[4];
  const float* W_attn_src  = (const float*)d_in[5];
  const float* W_attn_dst  = (const float*)d_in[6];
  const float* W_attn_edge = (const float*)d_in[7];
  const float* scale       = (const float*)d_in[8];
  const float* offset      = (const float*)d_in[9];
  const float* W_agg       = (const float*)d_in[10];
  const float* b_agg       = (const float*)d_in[11];
  const float* W_dst       = (const float*)d_in[12];
  const float* b_dst       = (const float*)d_in[13];
  const float* W_apply     = (const float*)d_in[14];
  const float* b_apply     = (const float*)d_in[15];
  float* out = (float*)d_out;

  char* ws = (char*)d_ws;
  size_t off = 0;
  auto take = [&](size_t bytes) {
    size_t o = off;
    off = (off + bytes + 255) & ~(size_t)255;
    return o;
  };
  size_t fc_src_off = take((size_t)NN * HF * 4);
  size_t fc_dst_off = take((size_t)NN * HF * 4);
  size_t asrc_off   = take((size_t)NN * 4 * 4);
  size_t adst_off   = take((size_t)NN * 4 * 4);
  size_t ebuf_off   = take((size_t)NE * 4 * 4);
  size_t emax_off   = take((size_t)NN * 4 * 4);   // zeroed region start
  size_t zsum_off   = take((size_t)NN * 4 * 4);
  size_t cnt_off    = take((size_t)NN * 4);       // zeroed region end
  size_t offs_off   = take((size_t)(NN + 1) * 4);
  size_t bsum_off   = take((size_t)NB_SCAN * 4);
  size_t boff_off   = take((size_t)NB_SCAN * 4);
  size_t offcur_off = take((size_t)NN * 4);
  size_t ssort_off  = take((size_t)NE * 4);
  size_t asort_off  = take((size_t)NE * 4 * 4);
  size_t hout_off   = take((size_t)NN * HF * 4);
  if (ws_size < off) return;  // workspace too small -> loud failure

  float*    fc_src     = (float*)(ws + fc_src_off);
  float*    fc_dst     = (float*)(ws + fc_dst_off);
  float*    asrc       = (float*)(ws + asrc_off);
  float*    adst       = (float*)(ws + adst_off);
  float*    ebuf       = (float*)(ws + ebuf_off);
  unsigned* emax       = (unsigned*)(ws + emax_off);
  float*    zsum       = (float*)(ws + zsum_off);
  int*      cnt        = (int*)(ws + cnt_off);
  int*      offs       = (int*)(ws + offs_off);
  int*      bsum       = (int*)(ws + bsum_off);
  int*      boff       = (int*)(ws + boff_off);
  int*      offcur     = (int*)(ws + offcur_off);
  int*      src_sorted = (int*)(ws + ssort_off);
  float*    a_sorted   = (float*)(ws + asort_off);
  float*    h_out      = (float*)(ws + hout_off);

  // zero only the accumulators: emax (encoded-max identity), zsum, cnt
  hipMemsetAsync(ws + emax_off, 0, offs_off - emax_off, stream);

  node_proj_kernel<<<NN / 16, 256, 0, stream>>>(
      feat_src, W_src, W_dst, b_dst, W_attn_src, W_attn_dst,
      fc_src, fc_dst, asrc, adst);

  edge_pass1_kernel<<<(NE + 255) / 256, 256, 0, stream>>>(
      feat_edge, W_attn_edge, src_idx, dst_idx, asrc, adst, ebuf, emax, cnt);

  edge_pass2_kernel<<<(NE + 255) / 256, 256, 0, stream>>>(
      dst_idx, emax, ebuf, zsum);

  scan_block_kernel<<<NB_SCAN, 256, 0, stream>>>(cnt, offs, bsum);
  scan_bsum_kernel<<<1, 256, 0, stream>>>(bsum, boff);
  scan_final_kernel<<<NB_SCAN, 256, 0, stream>>>(offs, boff, offcur);

  scatter_kernel<<<(NE + 255) / 256, 256, 0, stream>>>(
      src_idx, dst_idx, ebuf, zsum, offcur, src_sorted, a_sorted);

  agg_kernel<<<NN, 128, 0, stream>>>(offs, src_sorted, a_sorted, fc_src, h_out);

  node_final_kernel<<<NN / 4, 128, 0, stream>>>(
      h_out, scale, offset, W_agg, b_agg, fc_dst, W_apply, b_apply, out);
}

// Round 4
// 590.462 us; speedup vs baseline: 1.5766x; 1.2867x over previous
//
#include <hip/hip_runtime.h>

#define NN 50000
#define NE 800000
#define DD 256
#define DE_DIM 16
#define HH 4
#define FF 32
#define HF 128
#define OUTD 32
#define SLOPE 0.2f
#define NB_SCAN ((NN + 255) / 256)   // 196

// MFMA proj tiling
#define BM 64
#define NCOL 272          // 128 + 128 + 4 + 4 + 8 pad
#define APAD 264          // A LDS row stride (bf16): 528B, 16B aligned
#define BTPAD 40          // Bt LDS row stride (bf16): 80B, 16B aligned

typedef short short8 __attribute__((ext_vector_type(8)));
typedef float f32x4 __attribute__((ext_vector_type(4)));
typedef unsigned short us4 __attribute__((ext_vector_type(4)));

// ---- monotonic float<->uint encoding for atomicMax on floats ----
__device__ __forceinline__ unsigned fenc(float f) {
  unsigned u = __float_as_uint(f);
  return u ^ ((u >> 31) ? 0xFFFFFFFFu : 0x80000000u);
}
__device__ __forceinline__ float fdec(unsigned u) {
  unsigned b = (u >> 31) ? (u ^ 0x80000000u) : ~u;
  return __uint_as_float(b);
}
// fp32 -> bf16 bits, round-to-nearest-even
__device__ __forceinline__ unsigned short bf16r(float x) {
  unsigned u = __float_as_uint(x);
  u += 0x7FFFu + ((u >> 16) & 1u);
  return (unsigned short)(u >> 16);
}

// ---- Prep: assemble transposed bf16 weight panel Bt[272][256] ----
__global__ __launch_bounds__(256) void bt_prep_kernel(
    const float* __restrict__ Wsrc, const float* __restrict__ Wdst,
    const float* __restrict__ Wasrc, const float* __restrict__ Wadst,
    unsigned short* __restrict__ Bt)
{
  int c = blockIdx.x;     // 0..271 (output column)
  int k = threadIdx.x;    // 0..255 (reduction index)
  float v = 0.f;
  if (c < 128)      v = Wsrc[(size_t)k * HF + c];
  else if (c < 256) v = Wdst[(size_t)k * HF + (c - 128)];
  else if (c < 260) v = Wasrc[(size_t)k * HH + (c - 256)];
  else if (c < 264) v = Wadst[(size_t)k * HH + (c - 260)];
  Bt[(size_t)c * DD + k] = bf16r(v);
}

// ---- Kernel 1': node projections via bf16 MFMA ----
// C[64 x 272] per block; 4 waves each own 16 rows x all 17 col-tiles.
__global__ __launch_bounds__(256) void mfma_proj_kernel(
    const float* __restrict__ feat, const unsigned short* __restrict__ Bt,
    const float* __restrict__ bdst,
    float* __restrict__ fc_src, float* __restrict__ fc_dst,
    float* __restrict__ asrc, float* __restrict__ adst)
{
  __shared__ unsigned short Albuf[BM * APAD];      // 33792 B
  __shared__ unsigned short Btbuf[NCOL * BTPAD];   // 21760 B
  const int tid  = threadIdx.x;
  const int wave = tid >> 6, lane = tid & 63;
  const int m0 = blockIdx.x * BM;

  // stage A panel [64][256] fp32->bf16 (row stride APAD)
  for (int i = tid; i < BM * 64; i += 256) {       // 64 float4-chunks per row
    int r = i >> 6, c4 = i & 63;
    int gr = m0 + r; if (gr >= NN) gr = NN - 1;    // clamp; writes guarded later
    float4 v = *(const float4*)(feat + (size_t)gr * DD + c4 * 4);
    us4 b; b.x = bf16r(v.x); b.y = bf16r(v.y); b.z = bf16r(v.z); b.w = bf16r(v.w);
    *(us4*)&Albuf[r * APAD + c4 * 4] = b;
  }

  f32x4 acc[17];
#pragma unroll
  for (int c0 = 0; c0 < 17; ++c0) acc[c0] = (f32x4){0.f, 0.f, 0.f, 0.f};

  const int arow = wave * 16 + (lane & 15);
  const int koff = (lane >> 4) * 8;

  for (int kk = 0; kk < 8; ++kk) {
    __syncthreads();   // Btbuf safe to overwrite (and A ready on kk==0)
    // stage Bt tile: Btbuf[c][0..31] = Bt[c][kk*32 .. +31]  (short8 = 8 bf16)
    for (int i = tid; i < NCOL * 4; i += 256) {
      int c = i >> 2, q = i & 3;
      *(short8*)&Btbuf[c * BTPAD + q * 8] =
          *(const short8*)(Bt + (size_t)c * DD + kk * 32 + q * 8);
    }
    __syncthreads();

    short8 a = *(const short8*)&Albuf[arow * APAD + kk * 32 + koff];
#pragma unroll
    for (int c0 = 0; c0 < 17; ++c0) {
      short8 b = *(const short8*)&Btbuf[(c0 * 16 + (lane & 15)) * BTPAD + koff];
      acc[c0] = __builtin_amdgcn_mfma_f32_16x16x32_bf16(a, b, acc[c0], 0, 0, 0);
    }
  }

  // epilogue: D row = (lane>>4)*4 + j, col = c0*16 + (lane&15)
  const int rbase = m0 + wave * 16 + (lane >> 4) * 4;
  const int cl = lane & 15;
#pragma unroll
  for (int c0 = 0; c0 < 17; ++c0) {
    int gcol = c0 * 16 + cl;
#pragma unroll
    for (int j = 0; j < 4; ++j) {
      int grow = rbase + j;
      if (grow >= NN) continue;
      float v = acc[c0][j];
      if (gcol < 128)      fc_src[(size_t)grow * HF + gcol] = v;
      else if (gcol < 256) fc_dst[(size_t)grow * HF + (gcol - 128)] = v + bdst[gcol - 128];
      else if (gcol < 260) asrc[(size_t)grow * HH + (gcol - 256)] = v;
      else if (gcol < 264) adst[(size_t)grow * HH + (gcol - 260)] = v;
    }
  }
}

// ---- Kernel 2: per-edge logits + segment max + dst-degree histogram ----
__global__ __launch_bounds__(256) void edge_pass1_kernel(
    const float* __restrict__ feat_edge, const float* __restrict__ Wae, // [16,4]
    const int* __restrict__ src_idx, const int* __restrict__ dst_idx,
    const float* __restrict__ asrc, const float* __restrict__ adst,
    float* __restrict__ ebuf, unsigned* __restrict__ emax,
    int* __restrict__ cnt)
{
  int e = blockIdx.x * 256 + threadIdx.x;
  if (e >= NE) return;
  int s = src_idx[e], d = dst_idx[e];

  float ae[HH] = {0.f, 0.f, 0.f, 0.f};
  const float4* fe4 = (const float4*)(feat_edge + (size_t)e * DE_DIM);
#pragma unroll
  for (int q = 0; q < 4; ++q) {
    float4 x = fe4[q];
    const float xs[4] = {x.x, x.y, x.z, x.w};
#pragma unroll
    for (int kk = 0; kk < 4; ++kk) {
      int k = q * 4 + kk;
#pragma unroll
      for (int h = 0; h < HH; ++h) ae[h] += xs[kk] * Wae[k * HH + h];
    }
  }
  float as[4], ad[4];
  *(float4*)as = *(const float4*)(asrc + (size_t)s * 4);
  *(float4*)ad = *(const float4*)(adst + (size_t)d * 4);

  float ev[4];
#pragma unroll
  for (int h = 0; h < HH; ++h) {
    float v = as[h] + ad[h] + ae[h];
    v = v >= 0.f ? v : SLOPE * v;
    ev[h] = v;
    atomicMax(&emax[(size_t)d * 4 + h], fenc(v));
  }
  *(float4*)(ebuf + (size_t)e * 4) = *(float4*)ev;
  atomicAdd(&cnt[d], 1);
}

// ---- Kernel 3: z = exp(e - max), segment sum ----
__global__ __launch_bounds__(256) void edge_pass2_kernel(
    const int* __restrict__ dst_idx, const unsigned* __restrict__ emax,
    float* __restrict__ ebuf, float* __restrict__ zsum)
{
  int e = blockIdx.x * 256 + threadIdx.x;
  if (e >= NE) return;
  int d = dst_idx[e];
  float ev[4];
  *(float4*)ev = *(const float4*)(ebuf + (size_t)e * 4);
#pragma unroll
  for (int h = 0; h < HH; ++h) {
    float m = fdec(emax[(size_t)d * 4 + h]);
    float z = expf(ev[h] - m);
    ev[h] = z;
    atomicAdd(&zsum[(size_t)d * 4 + h], z);
  }
  *(float4*)(ebuf + (size_t)e * 4) = *(float4*)ev;
}

// ---- CSR scan: block-local exclusive scan ----
__global__ __launch_bounds__(256) void scan_block_kernel(
    const int* __restrict__ cnt, int* __restrict__ offs, int* __restrict__ bsum)
{
  __shared__ int tmp[256];
  int t = threadIdx.x;
  int i = blockIdx.x * 256 + t;
  int v = (i < NN) ? cnt[i] : 0;
  tmp[t] = v;
  __syncthreads();
  for (int ofs = 1; ofs < 256; ofs <<= 1) {
    int add = (t >= ofs) ? tmp[t - ofs] : 0;
    __syncthreads();
    tmp[t] += add;
    __syncthreads();
  }
  if (i < NN) offs[i] = tmp[t] - v;   // exclusive, block-local
  if (t == 255) bsum[blockIdx.x] = tmp[255];
}

// ---- scan of block sums (single block; NB_SCAN <= 256) ----
__global__ __launch_bounds__(256) void scan_bsum_kernel(
    const int* __restrict__ bsum, int* __restrict__ boff)
{
  __shared__ int tmp[256];
  int t = threadIdx.x;
  int v = (t < NB_SCAN) ? bsum[t] : 0;
  tmp[t] = v;
  __syncthreads();
  for (int ofs = 1; ofs < 256; ofs <<= 1) {
    int add = (t >= ofs) ? tmp[t - ofs] : 0;
    __syncthreads();
    tmp[t] += add;
    __syncthreads();
  }
  if (t < NB_SCAN) boff[t] = tmp[t] - v;
}

// ---- finalize offsets; init scatter cursors ----
__global__ __launch_bounds__(256) void scan_final_kernel(
    int* __restrict__ offs, const int* __restrict__ boff, int* __restrict__ offcur)
{
  int i = blockIdx.x * 256 + threadIdx.x;
  if (i < NN) {
    int o = offs[i] + boff[blockIdx.x];
    offs[i] = o;
    offcur[i] = o;
  }
  if (i == 0) offs[NN] = NE;
}

// ---- scatter edges into CSR order with pre-normalized attention ----
__global__ __launch_bounds__(256) void scatter_kernel(
    const int* __restrict__ src_idx, const int* __restrict__ dst_idx,
    const float* __restrict__ ebuf, const float* __restrict__ zsum,
    int* __restrict__ offcur, int* __restrict__ src_sorted,
    float* __restrict__ a_sorted)
{
  int e = blockIdx.x * 256 + threadIdx.x;
  if (e >= NE) return;
  int d = dst_idx[e];
  int p = atomicAdd(&offcur[d], 1);
  float4 z  = *(const float4*)(ebuf + (size_t)e * 4);
  float4 zs = *(const float4*)(zsum + (size_t)d * 4);
  float4 a;
  a.x = z.x / zs.x; a.y = z.y / zs.y; a.z = z.z / zs.z; a.w = z.w / zs.w;
  src_sorted[p] = src_idx[e];
  *(float4*)(a_sorted + (size_t)p * 4) = a;
}

// ---- Kernel 4': gather-side aggregation, no atomics ----
__global__ __launch_bounds__(128) void agg_kernel(
    const int* __restrict__ offs, const int* __restrict__ src_sorted,
    const float* __restrict__ a_sorted, const float* __restrict__ fc_src,
    float* __restrict__ h_out)
{
  const int d = blockIdx.x;
  const int t = threadIdx.x;
  const int h = t >> 5;
  const int beg = offs[d], end = offs[d + 1];
  float acc = 0.f;
  for (int p = beg; p < end; ++p) {
    int s = src_sorted[p];
    float a = a_sorted[(size_t)p * 4 + h];
    acc += fc_src[(size_t)s * HF + t] * a;
  }
  h_out[(size_t)d * HF + t] = acc;
}

// ---- Kernel 5: per-head LN + W_agg GEMV + residual + W_apply GEMV ----
__global__ __launch_bounds__(128) void node_final_kernel(
    const float* __restrict__ h_in, const float* __restrict__ scale,
    const float* __restrict__ offset, const float* __restrict__ W_agg,
    const float* __restrict__ b_agg, const float* __restrict__ fc_dst,
    const float* __restrict__ W_apply, const float* __restrict__ b_apply,
    float* __restrict__ out)
{
  const int n0 = blockIdx.x * 4;
  const int t = threadIdx.x;
  __shared__ float hn[4][HF];
  __shared__ float rst[4][HF];
  const float sc = scale[t], of = offset[t];

#pragma unroll
  for (int nn = 0; nn < 4; ++nn) {
    float h = h_in[(size_t)(n0 + nn) * HF + t];
    float sum = h;
#pragma unroll
    for (int m = 1; m < 32; m <<= 1) sum += __shfl_xor(sum, m);
    float mean = sum * (1.f / 32.f);
    float dv = h - mean;
    float v2 = dv * dv;
#pragma unroll
    for (int m = 1; m < 32; m <<= 1) v2 += __shfl_xor(v2, m);
    float var = v2 * (1.f / 32.f) + 1e-9f;
    hn[nn][t] = dv * sc * rsqrtf(var) + of;
  }
  __syncthreads();

  float ba = b_agg[t];
  float acc[4] = {ba, ba, ba, ba};
  for (int k = 0; k < HF; ++k) {
    float w = W_agg[k * HF + t];
#pragma unroll
    for (int nn = 0; nn < 4; ++nn) acc[nn] += hn[nn][k] * w;
  }
#pragma unroll
  for (int nn = 0; nn < 4; ++nn) {
    float r = acc[nn] + fc_dst[(size_t)(n0 + nn) * HF + t];
    rst[nn][t] = r >= 0.f ? r : SLOPE * r;
  }
  __syncthreads();

  {
    int nn = t >> 5, c = t & 31;
    float o = b_apply[c];
    for (int k = 0; k < HF; ++k) o += rst[nn][k] * W_apply[k * OUTD + c];
    out[(size_t)(n0 + nn) * OUTD + c] = o;
  }
}

extern "C" void kernel_launch(void* const* d_in, const int* in_sizes, int n_in,
                              void* d_out, int out_size, void* d_ws, size_t ws_size,
                              hipStream_t stream)
{
  const float* feat_src    = (const float*)d_in[0];
  const float* feat_edge   = (const float*)d_in[1];
  const int*   src_idx     = (const int*)d_in[2];
  const int*   dst_idx     = (const int*)d_in[3];
  const float* W_src       = (const float*)d_in[4];
  const float* W_attn_src  = (const float*)d_in[5];
  const float* W_attn_dst  = (const float*)d_in[6];
  const float* W_attn_edge = (const float*)d_in[7];
  const float* scale       = (const float*)d_in[8];
  const float* offset      = (const float*)d_in[9];
  const float* W_agg       = (const float*)d_in[10];
  const float* b_agg       = (const float*)d_in[11];
  const float* W_dst       = (const float*)d_in[12];
  const float* b_dst       = (const float*)d_in[13];
  const float* W_apply     = (const float*)d_in[14];
  const float* b_apply     = (const float*)d_in[15];
  float* out = (float*)d_out;

  char* ws = (char*)d_ws;
  size_t off = 0;
  auto take = [&](size_t bytes) {
    size_t o = off;
    off = (off + bytes + 255) & ~(size_t)255;
    return o;
  };
  size_t fc_src_off = take((size_t)NN * HF * 4);
  size_t fc_dst_off = take((size_t)NN * HF * 4);
  size_t asrc_off   = take((size_t)NN * 4 * 4);
  size_t adst_off   = take((size_t)NN * 4 * 4);
  size_t ebuf_off   = take((size_t)NE * 4 * 4);
  size_t bt_off     = take((size_t)NCOL * DD * 2);
  size_t emax_off   = take((size_t)NN * 4 * 4);   // zeroed region start
  size_t zsum_off   = take((size_t)NN * 4 * 4);
  size_t cnt_off    = take((size_t)NN * 4);       // zeroed region end
  size_t offs_off   = take((size_t)(NN + 1) * 4);
  size_t bsum_off   = take((size_t)NB_SCAN * 4);
  size_t boff_off   = take((size_t)NB_SCAN * 4);
  size_t offcur_off = take((size_t)NN * 4);
  size_t ssort_off  = take((size_t)NE * 4);
  size_t asort_off  = take((size_t)NE * 4 * 4);
  size_t hout_off   = take((size_t)NN * HF * 4);
  if (ws_size < off) return;  // workspace too small -> loud failure

  float*          fc_src     = (float*)(ws + fc_src_off);
  float*          fc_dst     = (float*)(ws + fc_dst_off);
  float*          asrc       = (float*)(ws + asrc_off);
  float*          adst       = (float*)(ws + adst_off);
  float*          ebuf       = (float*)(ws + ebuf_off);
  unsigned short* Bt         = (unsigned short*)(ws + bt_off);
  unsigned*       emax       = (unsigned*)(ws + emax_off);
  float*          zsum       = (float*)(ws + zsum_off);
  int*            cnt        = (int*)(ws + cnt_off);
  int*            offs       = (int*)(ws + offs_off);
  int*            bsum       = (int*)(ws + bsum_off);
  int*            boff       = (int*)(ws + boff_off);
  int*            offcur     = (int*)(ws + offcur_off);
  int*            src_sorted = (int*)(ws + ssort_off);
  float*          a_sorted   = (float*)(ws + asort_off);
  float*          h_out      = (float*)(ws + hout_off);

  // zero only the accumulators: emax (encoded-max identity), zsum, cnt
  hipMemsetAsync(ws + emax_off, 0, offs_off - emax_off, stream);

  bt_prep_kernel<<<NCOL, 256, 0, stream>>>(W_src, W_dst, W_attn_src, W_attn_dst, Bt);

  mfma_proj_kernel<<<(NN + BM - 1) / BM, 256, 0, stream>>>(
      feat_src, Bt, b_dst, fc_src, fc_dst, asrc, adst);

  edge_pass1_kernel<<<(NE + 255) / 256, 256, 0, stream>>>(
      feat_edge, W_attn_edge, src_idx, dst_idx, asrc, adst, ebuf, emax, cnt);

  edge_pass2_kernel<<<(NE + 255) / 256, 256, 0, stream>>>(
      dst_idx, emax, ebuf, zsum);

  scan_block_kernel<<<NB_SCAN, 256, 0, stream>>>(cnt, offs, bsum);
  scan_bsum_kernel<<<1, 256, 0, stream>>>(bsum, boff);
  scan_final_kernel<<<NB_SCAN, 256, 0, stream>>>(offs, boff, offcur);

  scatter_kernel<<<(NE + 255) / 256, 256, 0, stream>>>(
      src_idx, dst_idx, ebuf, zsum, offcur, src_sorted, a_sorted);

  agg_kernel<<<NN, 128, 0, stream>>>(offs, src_sorted, a_sorted, fc_src, h_out);

  node_final_kernel<<<NN / 4, 128, 0, stream>>>(
      h_out, scale, offset, W_agg, b_agg, fc_dst, W_apply, b_apply, out);
}

// Round 5
// 331.765 us; speedup vs baseline: 2.8059x; 1.7798x over previous
//
#include <hip/hip_runtime.h>

#define NN 50000
#define NE 800000
#define DD 256
#define DE_DIM 16
#define HH 4
#define FF 32
#define HF 128
#define OUTD 32
#define SLOPE 0.2f
#define NB_SCAN ((NN + 255) / 256)   // 196

// MFMA proj tiling
#define BM 64
#define NCOL 272          // 128 + 128 + 4 + 4 + 8 pad
#define APAD 264          // A LDS row stride (bf16): 528B, 16B aligned
#define BTPAD 40          // Bt LDS row stride (bf16): 80B, 16B aligned

typedef short short8 __attribute__((ext_vector_type(8)));
typedef float f32x4 __attribute__((ext_vector_type(4)));
typedef unsigned short us4 __attribute__((ext_vector_type(4)));

// fp32 -> bf16 bits, round-to-nearest-even
__device__ __forceinline__ unsigned short bf16r(float x) {
  unsigned u = __float_as_uint(x);
  u += 0x7FFFu + ((u >> 16) & 1u);
  return (unsigned short)(u >> 16);
}

// ---- Prep: assemble transposed bf16 weight panel Bt[272][256] ----
__global__ __launch_bounds__(256) void bt_prep_kernel(
    const float* __restrict__ Wsrc, const float* __restrict__ Wdst,
    const float* __restrict__ Wasrc, const float* __restrict__ Wadst,
    unsigned short* __restrict__ Bt)
{
  int c = blockIdx.x;     // 0..271 (output column)
  int k = threadIdx.x;    // 0..255 (reduction index)
  float v = 0.f;
  if (c < 128)      v = Wsrc[(size_t)k * HF + c];
  else if (c < 256) v = Wdst[(size_t)k * HF + (c - 128)];
  else if (c < 260) v = Wasrc[(size_t)k * HH + (c - 256)];
  else if (c < 264) v = Wadst[(size_t)k * HH + (c - 260)];
  Bt[(size_t)c * DD + k] = bf16r(v);
}

// ---- Kernel 1': node projections via bf16 MFMA ----
__global__ __launch_bounds__(256) void mfma_proj_kernel(
    const float* __restrict__ feat, const unsigned short* __restrict__ Bt,
    const float* __restrict__ bdst,
    float* __restrict__ fc_src, float* __restrict__ fc_dst,
    float* __restrict__ asrc, float* __restrict__ adst)
{
  __shared__ unsigned short Albuf[BM * APAD];      // 33792 B
  __shared__ unsigned short Btbuf[NCOL * BTPAD];   // 21760 B
  const int tid  = threadIdx.x;
  const int wave = tid >> 6, lane = tid & 63;
  const int m0 = blockIdx.x * BM;

  for (int i = tid; i < BM * 64; i += 256) {
    int r = i >> 6, c4 = i & 63;
    int gr = m0 + r; if (gr >= NN) gr = NN - 1;
    float4 v = *(const float4*)(feat + (size_t)gr * DD + c4 * 4);
    us4 b; b.x = bf16r(v.x); b.y = bf16r(v.y); b.z = bf16r(v.z); b.w = bf16r(v.w);
    *(us4*)&Albuf[r * APAD + c4 * 4] = b;
  }

  f32x4 acc[17];
#pragma unroll
  for (int c0 = 0; c0 < 17; ++c0) acc[c0] = (f32x4){0.f, 0.f, 0.f, 0.f};

  const int arow = wave * 16 + (lane & 15);
  const int koff = (lane >> 4) * 8;

  for (int kk = 0; kk < 8; ++kk) {
    __syncthreads();
    for (int i = tid; i < NCOL * 4; i += 256) {
      int c = i >> 2, q = i & 3;
      *(short8*)&Btbuf[c * BTPAD + q * 8] =
          *(const short8*)(Bt + (size_t)c * DD + kk * 32 + q * 8);
    }
    __syncthreads();

    short8 a = *(const short8*)&Albuf[arow * APAD + kk * 32 + koff];
#pragma unroll
    for (int c0 = 0; c0 < 17; ++c0) {
      short8 b = *(const short8*)&Btbuf[(c0 * 16 + (lane & 15)) * BTPAD + koff];
      acc[c0] = __builtin_amdgcn_mfma_f32_16x16x32_bf16(a, b, acc[c0], 0, 0, 0);
    }
  }

  const int rbase = m0 + wave * 16 + (lane >> 4) * 4;
  const int cl = lane & 15;
#pragma unroll
  for (int c0 = 0; c0 < 17; ++c0) {
    int gcol = c0 * 16 + cl;
#pragma unroll
    for (int j = 0; j < 4; ++j) {
      int grow = rbase + j;
      if (grow >= NN) continue;
      float v = acc[c0][j];
      if (gcol < 128)      fc_src[(size_t)grow * HF + gcol] = v;
      else if (gcol < 256) fc_dst[(size_t)grow * HF + (gcol - 128)] = v + bdst[gcol - 128];
      else if (gcol < 260) asrc[(size_t)grow * HH + (gcol - 256)] = v;
      else if (gcol < 264) adst[(size_t)grow * HH + (gcol - 260)] = v;
    }
  }
}

// ---- dst-degree histogram ----
__global__ __launch_bounds__(256) void hist_kernel(
    const int* __restrict__ dst_idx, int* __restrict__ cnt)
{
  int e = blockIdx.x * 256 + threadIdx.x;
  if (e < NE) atomicAdd(&cnt[dst_idx[e]], 1);
}

// ---- CSR scan: block-local exclusive scan ----
__global__ __launch_bounds__(256) void scan_block_kernel(
    const int* __restrict__ cnt, int* __restrict__ offs, int* __restrict__ bsum)
{
  __shared__ int tmp[256];
  int t = threadIdx.x;
  int i = blockIdx.x * 256 + t;
  int v = (i < NN) ? cnt[i] : 0;
  tmp[t] = v;
  __syncthreads();
  for (int ofs = 1; ofs < 256; ofs <<= 1) {
    int add = (t >= ofs) ? tmp[t - ofs] : 0;
    __syncthreads();
    tmp[t] += add;
    __syncthreads();
  }
  if (i < NN) offs[i] = tmp[t] - v;
  if (t == 255) bsum[blockIdx.x] = tmp[255];
}

__global__ __launch_bounds__(256) void scan_bsum_kernel(
    const int* __restrict__ bsum, int* __restrict__ boff)
{
  __shared__ int tmp[256];
  int t = threadIdx.x;
  int v = (t < NB_SCAN) ? bsum[t] : 0;
  tmp[t] = v;
  __syncthreads();
  for (int ofs = 1; ofs < 256; ofs <<= 1) {
    int add = (t >= ofs) ? tmp[t - ofs] : 0;
    __syncthreads();
    tmp[t] += add;
    __syncthreads();
  }
  if (t < NB_SCAN) boff[t] = tmp[t] - v;
}

__global__ __launch_bounds__(256) void scan_final_kernel(
    int* __restrict__ offs, const int* __restrict__ boff, int* __restrict__ offcur)
{
  int i = blockIdx.x * 256 + threadIdx.x;
  if (i < NN) {
    int o = offs[i] + boff[blockIdx.x];
    offs[i] = o;
    offcur[i] = o;
  }
  if (i == 0) offs[NN] = NE;
}

// ---- fused: per-edge logits + scatter into CSR order (no softmax here) ----
__global__ __launch_bounds__(256) void scatter_logits_kernel(
    const float* __restrict__ feat_edge, const float* __restrict__ Wae, // [16,4]
    const int* __restrict__ src_idx, const int* __restrict__ dst_idx,
    const float* __restrict__ asrc, const float* __restrict__ adst,
    int* __restrict__ offcur, int* __restrict__ src_sorted,
    float* __restrict__ esorted)
{
  int e = blockIdx.x * 256 + threadIdx.x;
  if (e >= NE) return;
  int s = src_idx[e], d = dst_idx[e];

  float ae[HH] = {0.f, 0.f, 0.f, 0.f};
  const float4* fe4 = (const float4*)(feat_edge + (size_t)e * DE_DIM);
#pragma unroll
  for (int q = 0; q < 4; ++q) {
    float4 x = fe4[q];
    const float xs[4] = {x.x, x.y, x.z, x.w};
#pragma unroll
    for (int kk = 0; kk < 4; ++kk) {
      int k = q * 4 + kk;
#pragma unroll
      for (int h = 0; h < HH; ++h) ae[h] += xs[kk] * Wae[k * HH + h];
    }
  }
  float as[4], ad[4];
  *(float4*)as = *(const float4*)(asrc + (size_t)s * 4);
  *(float4*)ad = *(const float4*)(adst + (size_t)d * 4);

  float ev[4];
#pragma unroll
  for (int h = 0; h < HH; ++h) {
    float v = as[h] + ad[h] + ae[h];
    ev[h] = v >= 0.f ? v : SLOPE * v;
  }
  int p = atomicAdd(&offcur[d], 1);
  src_sorted[p] = s;
  *(float4*)(esorted + (size_t)p * 4) = *(float4*)ev;
}

// ---- fused segment softmax + aggregation: zero atomics ----
// One 128-thread block per dst; thread t owns feature t, head h=t>>5.
// Pass 1: per-head max (broadcast reads). Pass 2: unnormalized weighted
// accumulate + exp-sum. Normalize once at the end.
__global__ __launch_bounds__(128) void agg_fused_kernel(
    const int* __restrict__ offs, const int* __restrict__ src_sorted,
    const float* __restrict__ esorted, const float* __restrict__ fc_src,
    float* __restrict__ h_out)
{
  const int d = blockIdx.x;
  const int t = threadIdx.x;
  const int h = t >> 5;
  const int beg = offs[d], end = offs[d + 1];

  float m = -3.4e38f;
  for (int p = beg; p < end; ++p)
    m = fmaxf(m, esorted[(size_t)p * 4 + h]);

  float ssum = 0.f, acc = 0.f;
  for (int p = beg; p < end; ++p) {
    int s = src_sorted[p];
    float z = __expf(esorted[(size_t)p * 4 + h] - m);
    ssum += z;
    acc += fc_src[(size_t)s * HF + t] * z;
  }
  h_out[(size_t)d * HF + t] = (end > beg) ? acc / ssum : 0.f;
}

// ---- Kernel 5: per-head LN + W_agg GEMV + residual + W_apply GEMV ----
__global__ __launch_bounds__(128) void node_final_kernel(
    const float* __restrict__ h_in, const float* __restrict__ scale,
    const float* __restrict__ offset, const float* __restrict__ W_agg,
    const float* __restrict__ b_agg, const float* __restrict__ fc_dst,
    const float* __restrict__ W_apply, const float* __restrict__ b_apply,
    float* __restrict__ out)
{
  const int n0 = blockIdx.x * 4;
  const int t = threadIdx.x;
  __shared__ float hn[4][HF];
  __shared__ float rst[4][HF];
  const float sc = scale[t], of = offset[t];

#pragma unroll
  for (int nn = 0; nn < 4; ++nn) {
    float h = h_in[(size_t)(n0 + nn) * HF + t];
    float sum = h;
#pragma unroll
    for (int m = 1; m < 32; m <<= 1) sum += __shfl_xor(sum, m);
    float mean = sum * (1.f / 32.f);
    float dv = h - mean;
    float v2 = dv * dv;
#pragma unroll
    for (int m = 1; m < 32; m <<= 1) v2 += __shfl_xor(v2, m);
    float var = v2 * (1.f / 32.f) + 1e-9f;
    hn[nn][t] = dv * sc * rsqrtf(var) + of;
  }
  __syncthreads();

  float ba = b_agg[t];
  float acc[4] = {ba, ba, ba, ba};
  for (int k = 0; k < HF; ++k) {
    float w = W_agg[k * HF + t];
#pragma unroll
    for (int nn = 0; nn < 4; ++nn) acc[nn] += hn[nn][k] * w;
  }
#pragma unroll
  for (int nn = 0; nn < 4; ++nn) {
    float r = acc[nn] + fc_dst[(size_t)(n0 + nn) * HF + t];
    rst[nn][t] = r >= 0.f ? r : SLOPE * r;
  }
  __syncthreads();

  {
    int nn = t >> 5, c = t & 31;
    float o = b_apply[c];
    for (int k = 0; k < HF; ++k) o += rst[nn][k] * W_apply[k * OUTD + c];
    out[(size_t)(n0 + nn) * OUTD + c] = o;
  }
}

extern "C" void kernel_launch(void* const* d_in, const int* in_sizes, int n_in,
                              void* d_out, int out_size, void* d_ws, size_t ws_size,
                              hipStream_t stream)
{
  const float* feat_src    = (const float*)d_in[0];
  const float* feat_edge   = (const float*)d_in[1];
  const int*   src_idx     = (const int*)d_in[2];
  const int*   dst_idx     = (const int*)d_in[3];
  const float* W_src       = (const float*)d_in[4];
  const float* W_attn_src  = (const float*)d_in[5];
  const float* W_attn_dst  = (const float*)d_in[6];
  const float* W_attn_edge = (const float*)d_in[7];
  const float* scale       = (const float*)d_in[8];
  const float* offset      = (const float*)d_in[9];
  const float* W_agg       = (const float*)d_in[10];
  const float* b_agg       = (const float*)d_in[11];
  const float* W_dst       = (const float*)d_in[12];
  const float* b_dst       = (const float*)d_in[13];
  const float* W_apply     = (const float*)d_in[14];
  const float* b_apply     = (const float*)d_in[15];
  float* out = (float*)d_out;

  char* ws = (char*)d_ws;
  size_t off = 0;
  auto take = [&](size_t bytes) {
    size_t o = off;
    off = (off + bytes + 255) & ~(size_t)255;
    return o;
  };
  size_t fc_src_off = take((size_t)NN * HF * 4);
  size_t fc_dst_off = take((size_t)NN * HF * 4);
  size_t asrc_off   = take((size_t)NN * 4 * 4);
  size_t adst_off   = take((size_t)NN * 4 * 4);
  size_t bt_off     = take((size_t)NCOL * DD * 2);
  size_t cnt_off    = take((size_t)NN * 4);       // zeroed
  size_t offs_off   = take((size_t)(NN + 1) * 4);
  size_t bsum_off   = take((size_t)NB_SCAN * 4);
  size_t boff_off   = take((size_t)NB_SCAN * 4);
  size_t offcur_off = take((size_t)NN * 4);
  size_t ssort_off  = take((size_t)NE * 4);
  size_t esort_off  = take((size_t)NE * 4 * 4);
  size_t hout_off   = take((size_t)NN * HF * 4);
  if (ws_size < off) return;  // workspace too small -> loud failure

  float*          fc_src     = (float*)(ws + fc_src_off);
  float*          fc_dst     = (float*)(ws + fc_dst_off);
  float*          asrc       = (float*)(ws + asrc_off);
  float*          adst       = (float*)(ws + adst_off);
  unsigned short* Bt         = (unsigned short*)(ws + bt_off);
  int*            cnt        = (int*)(ws + cnt_off);
  int*            offs       = (int*)(ws + offs_off);
  int*            bsum       = (int*)(ws + bsum_off);
  int*            boff       = (int*)(ws + boff_off);
  int*            offcur     = (int*)(ws + offcur_off);
  int*            src_sorted = (int*)(ws + ssort_off);
  float*          esorted    = (float*)(ws + esort_off);
  float*          h_out      = (float*)(ws + hout_off);

  hipMemsetAsync(ws + cnt_off, 0, (size_t)NN * 4, stream);

  bt_prep_kernel<<<NCOL, 256, 0, stream>>>(W_src, W_dst, W_attn_src, W_attn_dst, Bt);

  hist_kernel<<<(NE + 255) / 256, 256, 0, stream>>>(dst_idx, cnt);

  mfma_proj_kernel<<<(NN + BM - 1) / BM, 256, 0, stream>>>(
      feat_src, Bt, b_dst, fc_src, fc_dst, asrc, adst);

  scan_block_kernel<<<NB_SCAN, 256, 0, stream>>>(cnt, offs, bsum);
  scan_bsum_kernel<<<1, 256, 0, stream>>>(bsum, boff);
  scan_final_kernel<<<NB_SCAN, 256, 0, stream>>>(offs, boff, offcur);

  scatter_logits_kernel<<<(NE + 255) / 256, 256, 0, stream>>>(
      feat_edge, W_attn_edge, src_idx, dst_idx, asrc, adst,
      offcur, src_sorted, esorted);

  agg_fused_kernel<<<NN, 128, 0, stream>>>(
      offs, src_sorted, esorted, fc_src, h_out);

  node_final_kernel<<<NN / 4, 128, 0, stream>>>(
      h_out, scale, offset, W_agg, b_agg, fc_dst, W_apply, b_apply, out);
}

// Round 6
// 267.914 us; speedup vs baseline: 3.4746x; 1.2383x over previous
//
#include <hip/hip_runtime.h>

#define NN 50000
#define NE 800000
#define DD 256
#define DE_DIM 16
#define HH 4
#define FF 32
#define HF 128
#define OUTD 32
#define SLOPE 0.2f
#define NB_SCAN ((NN + 255) / 256)   // 196

// MFMA proj tiling
#define BM 64
#define NCOL 272          // 128 + 128 + 4 + 4 + 8 pad
#define APAD 264          // A LDS row stride (bf16): 528B, 16B aligned
#define BTPAD 40          // Bt LDS row stride (bf16): 80B, 16B aligned

typedef short short8 __attribute__((ext_vector_type(8)));
typedef float f32x4 __attribute__((ext_vector_type(4)));
typedef unsigned short us4 __attribute__((ext_vector_type(4)));

// fp32 -> bf16 bits, round-to-nearest-even
__device__ __forceinline__ unsigned short bf16r(float x) {
  unsigned u = __float_as_uint(x);
  u += 0x7FFFu + ((u >> 16) & 1u);
  return (unsigned short)(u >> 16);
}

// ---- Prep: assemble transposed bf16 weight panel Bt[272][256] ----
__global__ __launch_bounds__(256) void bt_prep_kernel(
    const float* __restrict__ Wsrc, const float* __restrict__ Wdst,
    const float* __restrict__ Wasrc, const float* __restrict__ Wadst,
    unsigned short* __restrict__ Bt)
{
  int c = blockIdx.x;     // 0..271 (output column)
  int k = threadIdx.x;    // 0..255 (reduction index)
  float v = 0.f;
  if (c < 128)      v = Wsrc[(size_t)k * HF + c];
  else if (c < 256) v = Wdst[(size_t)k * HF + (c - 128)];
  else if (c < 260) v = Wasrc[(size_t)k * HH + (c - 256)];
  else if (c < 264) v = Wadst[(size_t)k * HH + (c - 260)];
  Bt[(size_t)c * DD + k] = bf16r(v);
}

// ---- Kernel 1': node projections via bf16 MFMA ----
__global__ __launch_bounds__(256) void mfma_proj_kernel(
    const float* __restrict__ feat, const unsigned short* __restrict__ Bt,
    const float* __restrict__ bdst,
    float* __restrict__ fc_src, float* __restrict__ fc_dst,
    float* __restrict__ asrc, float* __restrict__ adst)
{
  __shared__ unsigned short Albuf[BM * APAD];      // 33792 B
  __shared__ unsigned short Btbuf[NCOL * BTPAD];   // 21760 B
  const int tid  = threadIdx.x;
  const int wave = tid >> 6, lane = tid & 63;
  const int m0 = blockIdx.x * BM;

  for (int i = tid; i < BM * 64; i += 256) {
    int r = i >> 6, c4 = i & 63;
    int gr = m0 + r; if (gr >= NN) gr = NN - 1;
    float4 v = *(const float4*)(feat + (size_t)gr * DD + c4 * 4);
    us4 b; b.x = bf16r(v.x); b.y = bf16r(v.y); b.z = bf16r(v.z); b.w = bf16r(v.w);
    *(us4*)&Albuf[r * APAD + c4 * 4] = b;
  }

  f32x4 acc[17];
#pragma unroll
  for (int c0 = 0; c0 < 17; ++c0) acc[c0] = (f32x4){0.f, 0.f, 0.f, 0.f};

  const int arow = wave * 16 + (lane & 15);
  const int koff = (lane >> 4) * 8;

  for (int kk = 0; kk < 8; ++kk) {
    __syncthreads();
    for (int i = tid; i < NCOL * 4; i += 256) {
      int c = i >> 2, q = i & 3;
      *(short8*)&Btbuf[c * BTPAD + q * 8] =
          *(const short8*)(Bt + (size_t)c * DD + kk * 32 + q * 8);
    }
    __syncthreads();

    short8 a = *(const short8*)&Albuf[arow * APAD + kk * 32 + koff];
#pragma unroll
    for (int c0 = 0; c0 < 17; ++c0) {
      short8 b = *(const short8*)&Btbuf[(c0 * 16 + (lane & 15)) * BTPAD + koff];
      acc[c0] = __builtin_amdgcn_mfma_f32_16x16x32_bf16(a, b, acc[c0], 0, 0, 0);
    }
  }

  const int rbase = m0 + wave * 16 + (lane >> 4) * 4;
  const int cl = lane & 15;
#pragma unroll
  for (int c0 = 0; c0 < 17; ++c0) {
    int gcol = c0 * 16 + cl;
#pragma unroll
    for (int j = 0; j < 4; ++j) {
      int grow = rbase + j;
      if (grow >= NN) continue;
      float v = acc[c0][j];
      if (gcol < 128)      fc_src[(size_t)grow * HF + gcol] = v;
      else if (gcol < 256) fc_dst[(size_t)grow * HF + (gcol - 128)] = v + bdst[gcol - 128];
      else if (gcol < 260) asrc[(size_t)grow * HH + (gcol - 256)] = v;
      else if (gcol < 264) adst[(size_t)grow * HH + (gcol - 260)] = v;
    }
  }
}

// ---- dst-degree histogram ----
__global__ __launch_bounds__(256) void hist_kernel(
    const int* __restrict__ dst_idx, int* __restrict__ cnt)
{
  int e = blockIdx.x * 256 + threadIdx.x;
  if (e < NE) atomicAdd(&cnt[dst_idx[e]], 1);
}

// ---- CSR scan: block-local exclusive scan ----
__global__ __launch_bounds__(256) void scan_block_kernel(
    const int* __restrict__ cnt, int* __restrict__ offs, int* __restrict__ bsum)
{
  __shared__ int tmp[256];
  int t = threadIdx.x;
  int i = blockIdx.x * 256 + t;
  int v = (i < NN) ? cnt[i] : 0;
  tmp[t] = v;
  __syncthreads();
  for (int ofs = 1; ofs < 256; ofs <<= 1) {
    int add = (t >= ofs) ? tmp[t - ofs] : 0;
    __syncthreads();
    tmp[t] += add;
    __syncthreads();
  }
  if (i < NN) offs[i] = tmp[t] - v;
  if (t == 255) bsum[blockIdx.x] = tmp[255];
}

__global__ __launch_bounds__(256) void scan_bsum_kernel(
    const int* __restrict__ bsum, int* __restrict__ boff)
{
  __shared__ int tmp[256];
  int t = threadIdx.x;
  int v = (t < NB_SCAN) ? bsum[t] : 0;
  tmp[t] = v;
  __syncthreads();
  for (int ofs = 1; ofs < 256; ofs <<= 1) {
    int add = (t >= ofs) ? tmp[t - ofs] : 0;
    __syncthreads();
    tmp[t] += add;
    __syncthreads();
  }
  if (t < NB_SCAN) boff[t] = tmp[t] - v;
}

__global__ __launch_bounds__(256) void scan_final_kernel(
    int* __restrict__ offs, const int* __restrict__ boff, int* __restrict__ offcur)
{
  int i = blockIdx.x * 256 + threadIdx.x;
  if (i < NN) {
    int o = offs[i] + boff[blockIdx.x];
    offs[i] = o;
    offcur[i] = o;
  }
  if (i == 0) offs[NN] = NE;
}

// ---- fused: per-edge logits + scatter into CSR order ----
__global__ __launch_bounds__(256) void scatter_logits_kernel(
    const float* __restrict__ feat_edge, const float* __restrict__ Wae, // [16,4]
    const int* __restrict__ src_idx, const int* __restrict__ dst_idx,
    const float* __restrict__ asrc, const float* __restrict__ adst,
    int* __restrict__ offcur, int* __restrict__ src_sorted,
    float* __restrict__ esorted)
{
  int e = blockIdx.x * 256 + threadIdx.x;
  if (e >= NE) return;
  int s = src_idx[e], d = dst_idx[e];

  float ae[HH] = {0.f, 0.f, 0.f, 0.f};
  const float4* fe4 = (const float4*)(feat_edge + (size_t)e * DE_DIM);
#pragma unroll
  for (int q = 0; q < 4; ++q) {
    float4 x = fe4[q];
    const float xs[4] = {x.x, x.y, x.z, x.w};
#pragma unroll
    for (int kk = 0; kk < 4; ++kk) {
      int k = q * 4 + kk;
#pragma unroll
      for (int h = 0; h < HH; ++h) ae[h] += xs[kk] * Wae[k * HH + h];
    }
  }
  float as[4], ad[4];
  *(float4*)as = *(const float4*)(asrc + (size_t)s * 4);
  *(float4*)ad = *(const float4*)(adst + (size_t)d * 4);

  float ev[4];
#pragma unroll
  for (int h = 0; h < HH; ++h) {
    float v = as[h] + ad[h] + ae[h];
    ev[h] = v >= 0.f ? v : SLOPE * v;
  }
  int p = atomicAdd(&offcur[d], 1);
  src_sorted[p] = s;
  *(float4*)(esorted + (size_t)p * 4) = *(float4*)ev;
}

// ---- fused segment softmax + aggregation: one wave per dst node ----
// Thread t owns features {2t, 2t+1}; head h = t>>4 (16 lanes per head).
// Pass 1: strided cooperative max + shfl reduce. Pass 2: 4x-unrolled
// accumulate with independent load chains. Normalize once.
__global__ __launch_bounds__(64) void agg_fused_kernel(
    const int* __restrict__ offs, const int* __restrict__ src_sorted,
    const float* __restrict__ esorted, const float* __restrict__ fc_src,
    float* __restrict__ h_out)
{
  const int d = blockIdx.x;
  const int t = threadIdx.x;        // 0..63
  const int fpair = t << 1;         // feature base (even)
  const int h = t >> 4;             // head, 16 lanes each
  const int beg = offs[d], end = offs[d + 1];

  // pass 1: cooperative per-head max
  float m = -3.4e38f;
  for (int p = beg + (t & 15); p < end; p += 16)
    m = fmaxf(m, esorted[(size_t)p * 4 + h]);
#pragma unroll
  for (int ofs = 1; ofs < 16; ofs <<= 1)
    m = fmaxf(m, __shfl_xor(m, ofs, 16));

  // pass 2: unrolled accumulate (4 independent load chains)
  float ssum = 0.f;
  float accx = 0.f, accy = 0.f;
  int p = beg;
  for (; p + 4 <= end; p += 4) {
    int s0 = src_sorted[p + 0];
    int s1 = src_sorted[p + 1];
    int s2 = src_sorted[p + 2];
    int s3 = src_sorted[p + 3];
    float e0 = esorted[(size_t)(p + 0) * 4 + h];
    float e1 = esorted[(size_t)(p + 1) * 4 + h];
    float e2 = esorted[(size_t)(p + 2) * 4 + h];
    float e3 = esorted[(size_t)(p + 3) * 4 + h];
    float2 fa = *(const float2*)&fc_src[(size_t)s0 * HF + fpair];
    float2 fb = *(const float2*)&fc_src[(size_t)s1 * HF + fpair];
    float2 fc_ = *(const float2*)&fc_src[(size_t)s2 * HF + fpair];
    float2 fd = *(const float2*)&fc_src[(size_t)s3 * HF + fpair];
    float z0 = __expf(e0 - m), z1 = __expf(e1 - m);
    float z2 = __expf(e2 - m), z3 = __expf(e3 - m);
    ssum += (z0 + z1) + (z2 + z3);
    accx += fa.x * z0 + fb.x * z1 + fc_.x * z2 + fd.x * z3;
    accy += fa.y * z0 + fb.y * z1 + fc_.y * z2 + fd.y * z3;
  }
  for (; p < end; ++p) {
    int s = src_sorted[p];
    float z = __expf(esorted[(size_t)p * 4 + h] - m);
    float2 f = *(const float2*)&fc_src[(size_t)s * HF + fpair];
    ssum += z;
    accx += f.x * z;
    accy += f.y * z;
  }
  float inv = (end > beg) ? 1.f / ssum : 0.f;
  float2 r; r.x = accx * inv; r.y = accy * inv;
  *(float2*)&h_out[(size_t)d * HF + fpair] = r;
}

// ---- Kernel 5: per-head LN + W_agg GEMV + residual + W_apply GEMV ----
// 8 nodes per 256-thread block (2 groups of 128 threads x 4 nodes).
__global__ __launch_bounds__(256) void node_final_kernel(
    const float* __restrict__ h_in, const float* __restrict__ scale,
    const float* __restrict__ offset, const float* __restrict__ W_agg,
    const float* __restrict__ b_agg, const float* __restrict__ fc_dst,
    const float* __restrict__ W_apply, const float* __restrict__ b_apply,
    float* __restrict__ out)
{
  const int t = threadIdx.x;          // 0..255
  const int tt = t & 127;             // feature
  const int grp = t >> 7;             // 0/1
  const int n0 = blockIdx.x * 8 + grp * 4;
  __shared__ float hn[8][HF];
  __shared__ float rst[8][HF];
  float* hng = &hn[grp * 4][0];
  float* rstg = &rst[grp * 4][0];
  const float sc = scale[tt], of = offset[tt];

#pragma unroll
  for (int nn = 0; nn < 4; ++nn) {
    float h = h_in[(size_t)(n0 + nn) * HF + tt];
    float sum = h;
#pragma unroll
    for (int m = 1; m < 32; m <<= 1) sum += __shfl_xor(sum, m);
    float mean = sum * (1.f / 32.f);
    float dv = h - mean;
    float v2 = dv * dv;
#pragma unroll
    for (int m = 1; m < 32; m <<= 1) v2 += __shfl_xor(v2, m);
    float var = v2 * (1.f / 32.f) + 1e-9f;
    hng[nn * HF + tt] = dv * sc * rsqrtf(var) + of;
  }
  __syncthreads();

  float ba = b_agg[tt];
  float acc[4] = {ba, ba, ba, ba};
  for (int k = 0; k < HF; ++k) {
    float w = W_agg[k * HF + tt];
#pragma unroll
    for (int nn = 0; nn < 4; ++nn) acc[nn] += hng[nn * HF + k] * w;
  }
#pragma unroll
  for (int nn = 0; nn < 4; ++nn) {
    float r = acc[nn] + fc_dst[(size_t)(n0 + nn) * HF + tt];
    rstg[nn * HF + tt] = r >= 0.f ? r : SLOPE * r;
  }
  __syncthreads();

  {
    int nn = t >> 5, c = t & 31;     // 8 nodes x 32 cols
    int gn = blockIdx.x * 8 + nn;
    float o = b_apply[c];
    for (int k = 0; k < HF; ++k) o += rst[nn][k] * W_apply[k * OUTD + c];
    out[(size_t)gn * OUTD + c] = o;
  }
}

extern "C" void kernel_launch(void* const* d_in, const int* in_sizes, int n_in,
                              void* d_out, int out_size, void* d_ws, size_t ws_size,
                              hipStream_t stream)
{
  const float* feat_src    = (const float*)d_in[0];
  const float* feat_edge   = (const float*)d_in[1];
  const int*   src_idx     = (const int*)d_in[2];
  const int*   dst_idx     = (const int*)d_in[3];
  const float* W_src       = (const float*)d_in[4];
  const float* W_attn_src  = (const float*)d_in[5];
  const float* W_attn_dst  = (const float*)d_in[6];
  const float* W_attn_edge = (const float*)d_in[7];
  const float* scale       = (const float*)d_in[8];
  const float* offset      = (const float*)d_in[9];
  const float* W_agg       = (const float*)d_in[10];
  const float* b_agg       = (const float*)d_in[11];
  const float* W_dst       = (const float*)d_in[12];
  const float* b_dst       = (const float*)d_in[13];
  const float* W_apply     = (const float*)d_in[14];
  const float* b_apply     = (const float*)d_in[15];
  float* out = (float*)d_out;

  char* ws = (char*)d_ws;
  size_t off = 0;
  auto take = [&](size_t bytes) {
    size_t o = off;
    off = (off + bytes + 255) & ~(size_t)255;
    return o;
  };
  size_t fc_src_off = take((size_t)NN * HF * 4);
  size_t fc_dst_off = take((size_t)NN * HF * 4);
  size_t asrc_off   = take((size_t)NN * 4 * 4);
  size_t adst_off   = take((size_t)NN * 4 * 4);
  size_t bt_off     = take((size_t)NCOL * DD * 2);
  size_t cnt_off    = take((size_t)NN * 4);       // zeroed
  size_t offs_off   = take((size_t)(NN + 1) * 4);
  size_t bsum_off   = take((size_t)NB_SCAN * 4);
  size_t boff_off   = take((size_t)NB_SCAN * 4);
  size_t offcur_off = take((size_t)NN * 4);
  size_t ssort_off  = take((size_t)NE * 4);
  size_t esort_off  = take((size_t)NE * 4 * 4);
  size_t hout_off   = take((size_t)NN * HF * 4);
  if (ws_size < off) return;  // workspace too small -> loud failure

  float*          fc_src     = (float*)(ws + fc_src_off);
  float*          fc_dst     = (float*)(ws + fc_dst_off);
  float*          asrc       = (float*)(ws + asrc_off);
  float*          adst       = (float*)(ws + adst_off);
  unsigned short* Bt         = (unsigned short*)(ws + bt_off);
  int*            cnt        = (int*)(ws + cnt_off);
  int*            offs       = (int*)(ws + offs_off);
  int*            bsum       = (int*)(ws + bsum_off);
  int*            boff       = (int*)(ws + boff_off);
  int*            offcur     = (int*)(ws + offcur_off);
  int*            src_sorted = (int*)(ws + ssort_off);
  float*          esorted    = (float*)(ws + esort_off);
  float*          h_out      = (float*)(ws + hout_off);

  hipMemsetAsync(ws + cnt_off, 0, (size_t)NN * 4, stream);

  bt_prep_kernel<<<NCOL, 256, 0, stream>>>(W_src, W_dst, W_attn_src, W_attn_dst, Bt);

  hist_kernel<<<(NE + 255) / 256, 256, 0, stream>>>(dst_idx, cnt);

  mfma_proj_kernel<<<(NN + BM - 1) / BM, 256, 0, stream>>>(
      feat_src, Bt, b_dst, fc_src, fc_dst, asrc, adst);

  scan_block_kernel<<<NB_SCAN, 256, 0, stream>>>(cnt, offs, bsum);
  scan_bsum_kernel<<<1, 256, 0, stream>>>(bsum, boff);
  scan_final_kernel<<<NB_SCAN, 256, 0, stream>>>(offs, boff, offcur);

  scatter_logits_kernel<<<(NE + 255) / 256, 256, 0, stream>>>(
      feat_edge, W_attn_edge, src_idx, dst_idx, asrc, adst,
      offcur, src_sorted, esorted);

  agg_fused_kernel<<<NN, 64, 0, stream>>>(
      offs, src_sorted, esorted, fc_src, h_out);

  node_final_kernel<<<(NN + 7) / 8, 256, 0, stream>>>(
      h_out, scale, offset, W_agg, b_agg, fc_dst, W_apply, b_apply, out);
}

// Round 7
// 248.772 us; speedup vs baseline: 3.7420x; 1.0769x over previous
//
#include <hip/hip_runtime.h>

#define NN 50000
#define NE 800000
#define DD 256
#define DE_DIM 16
#define HH 4
#define FF 32
#define HF 128
#define OUTD 32
#define SLOPE 0.2f
#define NB_SCAN ((NN + 255) / 256)   // 196

// MFMA proj tiling
#define BM 64
#define NCOL 272          // 128 + 128 + 4 + 4 + 8 pad
#define APAD 264          // A LDS row stride (bf16)
#define BTPAD 40          // Bt LDS row stride (bf16)
// node_final MFMA tiling
#define NFB 64            // nodes per block
#define FPAD 136          // LDS row stride (bf16): 272B; 16 rows -> 2-way (free)

typedef short short8 __attribute__((ext_vector_type(8)));
typedef float f32x4 __attribute__((ext_vector_type(4)));
typedef unsigned short us4 __attribute__((ext_vector_type(4)));

// fp32 -> bf16 bits, round-to-nearest-even
__device__ __forceinline__ unsigned short bf16r(float x) {
  unsigned u = __float_as_uint(x);
  u += 0x7FFFu + ((u >> 16) & 1u);
  return (unsigned short)(u >> 16);
}

// ---- Prep: assemble transposed bf16 weight panel Bt[272][256] ----
__global__ __launch_bounds__(256) void bt_prep_kernel(
    const float* __restrict__ Wsrc, const float* __restrict__ Wdst,
    const float* __restrict__ Wasrc, const float* __restrict__ Wadst,
    unsigned short* __restrict__ Bt)
{
  int c = blockIdx.x;     // 0..271
  int k = threadIdx.x;    // 0..255
  float v = 0.f;
  if (c < 128)      v = Wsrc[(size_t)k * HF + c];
  else if (c < 256) v = Wdst[(size_t)k * HF + (c - 128)];
  else if (c < 260) v = Wasrc[(size_t)k * HH + (c - 256)];
  else if (c < 264) v = Wadst[(size_t)k * HH + (c - 260)];
  Bt[(size_t)c * DD + k] = bf16r(v);
}

// ---- Prep: transposed bf16 W_agg [128][128] and W_apply [32][128] ----
__global__ __launch_bounds__(128) void wfin_prep_kernel(
    const float* __restrict__ W_agg, const float* __restrict__ W_apply,
    unsigned short* __restrict__ Wagg_t, unsigned short* __restrict__ Wapp_t)
{
  int c = blockIdx.x;     // 0..159
  int k = threadIdx.x;    // 0..127
  if (c < 128) Wagg_t[(size_t)c * HF + k] = bf16r(W_agg[(size_t)k * HF + c]);
  else         Wapp_t[(size_t)(c - 128) * HF + k] = bf16r(W_apply[(size_t)k * OUTD + (c - 128)]);
}

// ---- Kernel 1': node projections via bf16 MFMA ----
__global__ __launch_bounds__(256) void mfma_proj_kernel(
    const float* __restrict__ feat, const unsigned short* __restrict__ Bt,
    const float* __restrict__ bdst,
    float* __restrict__ fc_src, float* __restrict__ fc_dst,
    float* __restrict__ asrc, float* __restrict__ adst)
{
  __shared__ unsigned short Albuf[BM * APAD];      // 33792 B
  __shared__ unsigned short Btbuf[NCOL * BTPAD];   // 21760 B
  const int tid  = threadIdx.x;
  const int wave = tid >> 6, lane = tid & 63;
  const int m0 = blockIdx.x * BM;

  for (int i = tid; i < BM * 64; i += 256) {
    int r = i >> 6, c4 = i & 63;
    int gr = m0 + r; if (gr >= NN) gr = NN - 1;
    float4 v = *(const float4*)(feat + (size_t)gr * DD + c4 * 4);
    us4 b; b.x = bf16r(v.x); b.y = bf16r(v.y); b.z = bf16r(v.z); b.w = bf16r(v.w);
    *(us4*)&Albuf[r * APAD + c4 * 4] = b;
  }

  f32x4 acc[17];
#pragma unroll
  for (int c0 = 0; c0 < 17; ++c0) acc[c0] = (f32x4){0.f, 0.f, 0.f, 0.f};

  const int arow = wave * 16 + (lane & 15);
  const int koff = (lane >> 4) * 8;

  for (int kk = 0; kk < 8; ++kk) {
    __syncthreads();
    for (int i = tid; i < NCOL * 4; i += 256) {
      int c = i >> 2, q = i & 3;
      *(short8*)&Btbuf[c * BTPAD + q * 8] =
          *(const short8*)(Bt + (size_t)c * DD + kk * 32 + q * 8);
    }
    __syncthreads();

    short8 a = *(const short8*)&Albuf[arow * APAD + kk * 32 + koff];
#pragma unroll
    for (int c0 = 0; c0 < 17; ++c0) {
      short8 b = *(const short8*)&Btbuf[(c0 * 16 + (lane & 15)) * BTPAD + koff];
      acc[c0] = __builtin_amdgcn_mfma_f32_16x16x32_bf16(a, b, acc[c0], 0, 0, 0);
    }
  }

  const int rbase = m0 + wave * 16 + (lane >> 4) * 4;
  const int cl = lane & 15;
#pragma unroll
  for (int c0 = 0; c0 < 17; ++c0) {
    int gcol = c0 * 16 + cl;
#pragma unroll
    for (int j = 0; j < 4; ++j) {
      int grow = rbase + j;
      if (grow >= NN) continue;
      float v = acc[c0][j];
      if (gcol < 128)      fc_src[(size_t)grow * HF + gcol] = v;
      else if (gcol < 256) fc_dst[(size_t)grow * HF + (gcol - 128)] = v + bdst[gcol - 128];
      else if (gcol < 260) asrc[(size_t)grow * HH + (gcol - 256)] = v;
      else if (gcol < 264) adst[(size_t)grow * HH + (gcol - 260)] = v;
    }
  }
}

// ---- dst-degree histogram + per-edge rank (CSR slot precompute) ----
__global__ __launch_bounds__(256) void hist_kernel(
    const int* __restrict__ dst_idx, int* __restrict__ cnt,
    int* __restrict__ rank)
{
  int e = blockIdx.x * 256 + threadIdx.x;
  if (e < NE) rank[e] = atomicAdd(&cnt[dst_idx[e]], 1);
}

// ---- CSR scan: block-local exclusive scan ----
__global__ __launch_bounds__(256) void scan_block_kernel(
    const int* __restrict__ cnt, int* __restrict__ offs, int* __restrict__ bsum)
{
  __shared__ int tmp[256];
  int t = threadIdx.x;
  int i = blockIdx.x * 256 + t;
  int v = (i < NN) ? cnt[i] : 0;
  tmp[t] = v;
  __syncthreads();
  for (int ofs = 1; ofs < 256; ofs <<= 1) {
    int add = (t >= ofs) ? tmp[t - ofs] : 0;
    __syncthreads();
    tmp[t] += add;
    __syncthreads();
  }
  if (i < NN) offs[i] = tmp[t] - v;
  if (t == 255) bsum[blockIdx.x] = tmp[255];
}

__global__ __launch_bounds__(256) void scan_bsum_kernel(
    const int* __restrict__ bsum, int* __restrict__ boff)
{
  __shared__ int tmp[256];
  int t = threadIdx.x;
  int v = (t < NB_SCAN) ? bsum[t] : 0;
  tmp[t] = v;
  __syncthreads();
  for (int ofs = 1; ofs < 256; ofs <<= 1) {
    int add = (t >= ofs) ? tmp[t - ofs] : 0;
    __syncthreads();
    tmp[t] += add;
    __syncthreads();
  }
  if (t < NB_SCAN) boff[t] = tmp[t] - v;
}

__global__ __launch_bounds__(256) void scan_final_kernel(
    int* __restrict__ offs, const int* __restrict__ boff)
{
  int i = blockIdx.x * 256 + threadIdx.x;
  if (i < NN) offs[i] += boff[blockIdx.x];
  if (i == 0) offs[NN] = NE;
}

// ---- fused: per-edge logits + scatter into CSR slot (no atomics) ----
__global__ __launch_bounds__(256) void scatter_logits_kernel(
    const float* __restrict__ feat_edge, const float* __restrict__ Wae, // [16,4]
    const int* __restrict__ src_idx, const int* __restrict__ dst_idx,
    const float* __restrict__ asrc, const float* __restrict__ adst,
    const int* __restrict__ offs, const int* __restrict__ rank,
    int* __restrict__ src_sorted, float* __restrict__ esorted)
{
  int e = blockIdx.x * 256 + threadIdx.x;
  if (e >= NE) return;
  int s = src_idx[e], d = dst_idx[e];

  float ae[HH] = {0.f, 0.f, 0.f, 0.f};
  const float4* fe4 = (const float4*)(feat_edge + (size_t)e * DE_DIM);
#pragma unroll
  for (int q = 0; q < 4; ++q) {
    float4 x = fe4[q];
    const float xs[4] = {x.x, x.y, x.z, x.w};
#pragma unroll
    for (int kk = 0; kk < 4; ++kk) {
      int k = q * 4 + kk;
#pragma unroll
      for (int h = 0; h < HH; ++h) ae[h] += xs[kk] * Wae[k * HH + h];
    }
  }
  float as[4], ad[4];
  *(float4*)as = *(const float4*)(asrc + (size_t)s * 4);
  *(float4*)ad = *(const float4*)(adst + (size_t)d * 4);

  float ev[4];
#pragma unroll
  for (int h = 0; h < HH; ++h) {
    float v = as[h] + ad[h] + ae[h];
    ev[h] = v >= 0.f ? v : SLOPE * v;
  }
  int p = offs[d] + rank[e];
  src_sorted[p] = s;
  *(float4*)(esorted + (size_t)p * 4) = *(float4*)ev;
}

// ---- fused segment softmax + aggregation: one wave per dst node ----
__global__ __launch_bounds__(64) void agg_fused_kernel(
    const int* __restrict__ offs, const int* __restrict__ src_sorted,
    const float* __restrict__ esorted, const float* __restrict__ fc_src,
    float* __restrict__ h_out)
{
  const int d = blockIdx.x;
  const int t = threadIdx.x;        // 0..63
  const int fpair = t << 1;         // feature base (even)
  const int h = t >> 4;             // head, 16 lanes each
  const int beg = offs[d], end = offs[d + 1];

  float m = -3.4e38f;
  for (int p = beg + (t & 15); p < end; p += 16)
    m = fmaxf(m, esorted[(size_t)p * 4 + h]);
#pragma unroll
  for (int ofs = 1; ofs < 16; ofs <<= 1)
    m = fmaxf(m, __shfl_xor(m, ofs, 16));

  float ssum = 0.f;
  float accx = 0.f, accy = 0.f;
  int p = beg;
  for (; p + 4 <= end; p += 4) {
    int s0 = src_sorted[p + 0];
    int s1 = src_sorted[p + 1];
    int s2 = src_sorted[p + 2];
    int s3 = src_sorted[p + 3];
    float e0 = esorted[(size_t)(p + 0) * 4 + h];
    float e1 = esorted[(size_t)(p + 1) * 4 + h];
    float e2 = esorted[(size_t)(p + 2) * 4 + h];
    float e3 = esorted[(size_t)(p + 3) * 4 + h];
    float2 fa = *(const float2*)&fc_src[(size_t)s0 * HF + fpair];
    float2 fb = *(const float2*)&fc_src[(size_t)s1 * HF + fpair];
    float2 fc_ = *(const float2*)&fc_src[(size_t)s2 * HF + fpair];
    float2 fd = *(const float2*)&fc_src[(size_t)s3 * HF + fpair];
    float z0 = __expf(e0 - m), z1 = __expf(e1 - m);
    float z2 = __expf(e2 - m), z3 = __expf(e3 - m);
    ssum += (z0 + z1) + (z2 + z3);
    accx += fa.x * z0 + fb.x * z1 + fc_.x * z2 + fd.x * z3;
    accy += fa.y * z0 + fb.y * z1 + fc_.y * z2 + fd.y * z3;
  }
  for (; p < end; ++p) {
    int s = src_sorted[p];
    float z = __expf(esorted[(size_t)p * 4 + h] - m);
    float2 f = *(const float2*)&fc_src[(size_t)s * HF + fpair];
    ssum += z;
    accx += f.x * z;
    accy += f.y * z;
  }
  float inv = (end > beg) ? 1.f / ssum : 0.f;
  float2 r; r.x = accx * inv; r.y = accy * inv;
  *(float2*)&h_out[(size_t)d * HF + fpair] = r;
}

// ---- Kernel 5': LN + MFMA(W_agg) + residual/leaky + MFMA(W_apply) ----
// 64 nodes per 256-thread block.
__global__ __launch_bounds__(256) void node_final_mfma_kernel(
    const float* __restrict__ h_in, const float* __restrict__ scale,
    const float* __restrict__ offset,
    const unsigned short* __restrict__ Wagg_t, const float* __restrict__ b_agg,
    const float* __restrict__ fc_dst,
    const unsigned short* __restrict__ Wapp_t, const float* __restrict__ b_apply,
    float* __restrict__ out)
{
  __shared__ unsigned short Abuf[NFB * FPAD];     // 17408 B
  __shared__ unsigned short A2buf[NFB * FPAD];    // 17408 B
  __shared__ unsigned short Bagg[HF * FPAD];      // 34816 B
  __shared__ unsigned short Bapp[OUTD * FPAD];    // 8704 B
  const int tid = threadIdx.x;
  const int wave = tid >> 6, lane = tid & 63;
  const int n0 = blockIdx.x * NFB;

  // stage weights (short8 chunks)
  for (int i = tid; i < HF * 16; i += 256) {
    int c = i >> 4, q = i & 15;
    *(short8*)&Bagg[c * FPAD + q * 8] = *(const short8*)(Wagg_t + (size_t)c * HF + q * 8);
  }
  for (int i = tid; i < OUTD * 16; i += 256) {
    int c = i >> 4, q = i & 15;
    *(short8*)&Bapp[c * FPAD + q * 8] = *(const short8*)(Wapp_t + (size_t)c * HF + q * 8);
  }

  // LN: threads 0-127 -> nodes n0..n0+31, threads 128-255 -> n0+32..n0+63
  {
    const int half = tid >> 7;        // 0/1
    const int t = tid & 127;          // feature
    const float sc = scale[t], of = offset[t];
    for (int nn = 0; nn < 32; ++nn) {
      int row = half * 32 + nn;
      int node = n0 + row; if (node >= NN) node = NN - 1;
      float v = h_in[(size_t)node * HF + t];
      float sum = v;
#pragma unroll
      for (int m = 1; m < 32; m <<= 1) sum += __shfl_xor(sum, m);
      float mean = sum * (1.f / 32.f);
      float dv = v - mean;
      float v2 = dv * dv;
#pragma unroll
      for (int m = 1; m < 32; m <<= 1) v2 += __shfl_xor(v2, m);
      float var = v2 * (1.f / 32.f) + 1e-9f;
      Abuf[row * FPAD + t] = bf16r(dv * sc * rsqrtf(var) + of);
    }
  }
  __syncthreads();

  const int arow = wave * 16 + (lane & 15);
  const int koff = (lane >> 4) * 8;
  const int rbase = wave * 16 + (lane >> 4) * 4;
  const int cl = lane & 15;

  // MFMA 1: [64x128] @ [128x128]
  f32x4 acc1[8];
#pragma unroll
  for (int c0 = 0; c0 < 8; ++c0) acc1[c0] = (f32x4){0.f, 0.f, 0.f, 0.f};
#pragma unroll
  for (int ks = 0; ks < 4; ++ks) {
    short8 a = *(const short8*)&Abuf[arow * FPAD + ks * 32 + koff];
#pragma unroll
    for (int c0 = 0; c0 < 8; ++c0) {
      short8 b = *(const short8*)&Bagg[(c0 * 16 + cl) * FPAD + ks * 32 + koff];
      acc1[c0] = __builtin_amdgcn_mfma_f32_16x16x32_bf16(a, b, acc1[c0], 0, 0, 0);
    }
  }

  // epilogue 1: + b_agg + fc_dst, leaky, -> bf16 A2
#pragma unroll
  for (int c0 = 0; c0 < 8; ++c0) {
    int gcol = c0 * 16 + cl;
    float bg = b_agg[gcol];
#pragma unroll
    for (int j = 0; j < 4; ++j) {
      int row = rbase + j;
      int grow = n0 + row;
      float fd = (grow < NN) ? fc_dst[(size_t)grow * HF + gcol] : 0.f;
      float r = acc1[c0][j] + bg + fd;
      A2buf[row * FPAD + gcol] = bf16r(r >= 0.f ? r : SLOPE * r);
    }
  }
  __syncthreads();

  // MFMA 2: [64x128] @ [128x32]
  f32x4 acc2[2];
#pragma unroll
  for (int c0 = 0; c0 < 2; ++c0) acc2[c0] = (f32x4){0.f, 0.f, 0.f, 0.f};
#pragma unroll
  for (int ks = 0; ks < 4; ++ks) {
    short8 a = *(const short8*)&A2buf[arow * FPAD + ks * 32 + koff];
#pragma unroll
    for (int c0 = 0; c0 < 2; ++c0) {
      short8 b = *(const short8*)&Bapp[(c0 * 16 + cl) * FPAD + ks * 32 + koff];
      acc2[c0] = __builtin_amdgcn_mfma_f32_16x16x32_bf16(a, b, acc2[c0], 0, 0, 0);
    }
  }
#pragma unroll
  for (int c0 = 0; c0 < 2; ++c0) {
    int gcol = c0 * 16 + cl;
    float ba = b_apply[gcol];
#pragma unroll
    for (int j = 0; j < 4; ++j) {
      int grow = n0 + rbase + j;
      if (grow < NN) out[(size_t)grow * OUTD + gcol] = acc2[c0][j] + ba;
    }
  }
}

extern "C" void kernel_launch(void* const* d_in, const int* in_sizes, int n_in,
                              void* d_out, int out_size, void* d_ws, size_t ws_size,
                              hipStream_t stream)
{
  const float* feat_src    = (const float*)d_in[0];
  const float* feat_edge   = (const float*)d_in[1];
  const int*   src_idx     = (const int*)d_in[2];
  const int*   dst_idx     = (const int*)d_in[3];
  const float* W_src       = (const float*)d_in[4];
  const float* W_attn_src  = (const float*)d_in[5];
  const float* W_attn_dst  = (const float*)d_in[6];
  const float* W_attn_edge = (const float*)d_in[7];
  const float* scale       = (const float*)d_in[8];
  const float* offset      = (const float*)d_in[9];
  const float* W_agg       = (const float*)d_in[10];
  const float* b_agg       = (const float*)d_in[11];
  const float* W_dst       = (const float*)d_in[12];
  const float* b_dst       = (const float*)d_in[13];
  const float* W_apply     = (const float*)d_in[14];
  const float* b_apply     = (const float*)d_in[15];
  float* out = (float*)d_out;

  char* ws = (char*)d_ws;
  size_t off = 0;
  auto take = [&](size_t bytes) {
    size_t o = off;
    off = (off + bytes + 255) & ~(size_t)255;
    return o;
  };
  size_t fc_src_off = take((size_t)NN * HF * 4);
  size_t fc_dst_off = take((size_t)NN * HF * 4);
  size_t asrc_off   = take((size_t)NN * 4 * 4);
  size_t adst_off   = take((size_t)NN * 4 * 4);
  size_t bt_off     = take((size_t)NCOL * DD * 2);
  size_t wagg_off   = take((size_t)HF * HF * 2);
  size_t wapp_off   = take((size_t)OUTD * HF * 2);
  size_t cnt_off    = take((size_t)NN * 4);       // zeroed
  size_t offs_off   = take((size_t)(NN + 1) * 4);
  size_t bsum_off   = take((size_t)NB_SCAN * 4);
  size_t boff_off   = take((size_t)NB_SCAN * 4);
  size_t rank_off   = take((size_t)NE * 4);
  size_t ssort_off  = take((size_t)NE * 4);
  size_t esort_off  = take((size_t)NE * 4 * 4);
  size_t hout_off   = take((size_t)NN * HF * 4);
  if (ws_size < off) return;  // workspace too small -> loud failure

  float*          fc_src     = (float*)(ws + fc_src_off);
  float*          fc_dst     = (float*)(ws + fc_dst_off);
  float*          asrc       = (float*)(ws + asrc_off);
  float*          adst       = (float*)(ws + adst_off);
  unsigned short* Bt         = (unsigned short*)(ws + bt_off);
  unsigned short* Wagg_t     = (unsigned short*)(ws + wagg_off);
  unsigned short* Wapp_t     = (unsigned short*)(ws + wapp_off);
  int*            cnt        = (int*)(ws + cnt_off);
  int*            offs       = (int*)(ws + offs_off);
  int*            bsum       = (int*)(ws + bsum_off);
  int*            boff       = (int*)(ws + boff_off);
  int*            rank       = (int*)(ws + rank_off);
  int*            src_sorted = (int*)(ws + ssort_off);
  float*          esorted    = (float*)(ws + esort_off);
  float*          h_out      = (float*)(ws + hout_off);

  hipMemsetAsync(ws + cnt_off, 0, (size_t)NN * 4, stream);

  bt_prep_kernel<<<NCOL, 256, 0, stream>>>(W_src, W_dst, W_attn_src, W_attn_dst, Bt);
  wfin_prep_kernel<<<160, 128, 0, stream>>>(W_agg, W_apply, Wagg_t, Wapp_t);

  hist_kernel<<<(NE + 255) / 256, 256, 0, stream>>>(dst_idx, cnt, rank);

  mfma_proj_kernel<<<(NN + BM - 1) / BM, 256, 0, stream>>>(
      feat_src, Bt, b_dst, fc_src, fc_dst, asrc, adst);

  scan_block_kernel<<<NB_SCAN, 256, 0, stream>>>(cnt, offs, bsum);
  scan_bsum_kernel<<<1, 256, 0, stream>>>(bsum, boff);
  scan_final_kernel<<<NB_SCAN, 256, 0, stream>>>(offs, boff);

  scatter_logits_kernel<<<(NE + 255) / 256, 256, 0, stream>>>(
      feat_edge, W_attn_edge, src_idx, dst_idx, asrc, adst,
      offs, rank, src_sorted, esorted);

  agg_fused_kernel<<<NN, 64, 0, stream>>>(
      offs, src_sorted, esorted, fc_src, h_out);

  node_final_mfma_kernel<<<(NN + NFB - 1) / NFB, 256, 0, stream>>>(
      h_out, scale, offset, Wagg_t, b_agg, fc_dst, Wapp_t, b_apply, out);
}